// Round 9
// baseline (456.797 us; speedup 1.0000x reference)
//
#include <hip/hip_runtime.h>
#include <hip/hip_bf16.h>
#include <math.h>

#define B_ 2
#define L_ 1024
#define DM 1024
#define DIN 2048
#define DS 16
#define DTR 64
#define CHL 32      // chunk length
#define NCH 32      // chunks per sequence

typedef __attribute__((ext_vector_type(8))) short bf16x8;
typedef __attribute__((ext_vector_type(8))) unsigned short u16x8;
typedef __attribute__((ext_vector_type(4))) unsigned short u16x4;
typedef __attribute__((ext_vector_type(4))) float f32x4;
typedef unsigned short ushort_t;
typedef unsigned int uint_t;

__device__ __forceinline__ float sigmoidf_(float x) { return 1.f / (1.f + __expf(-x)); }
__device__ __forceinline__ ushort_t f2b(float f) {
    uint_t b = __float_as_uint(f);
    return (ushort_t)((b + 0x7FFFu + ((b >> 16) & 1u)) >> 16);
}
__device__ __forceinline__ float b2f(ushort_t u) {
    return __uint_as_float(((uint_t)u) << 16);
}

// fused f32 -> bf16 (RTN), 4 elems/thread
__global__ __launch_bounds__(256) void f2b_all_k(
    const float* __restrict__ s0, ushort_t* __restrict__ d0, int n0,
    const float* __restrict__ s1, ushort_t* __restrict__ d1, int n1,
    const float* __restrict__ s2, ushort_t* __restrict__ d2, int n2,
    const float* __restrict__ s3, ushort_t* __restrict__ d3, int n3,
    const float* __restrict__ s4, ushort_t* __restrict__ d4, int n4)
{
    int i = (blockIdx.x * 256 + threadIdx.x) * 4;
    const float* s; ushort_t* d;
    if (i < n0) { s = s0; d = d0; }
    else { i -= n0;
    if (i < n1) { s = s1; d = d1; }
    else { i -= n1;
    if (i < n2) { s = s2; d = d2; }
    else { i -= n2;
    if (i < n3) { s = s3; d = d3; }
    else { i -= n3;
    if (i < n4) { s = s4; d = d4; }
    else return; }}}}
    float4 v = *(const float4*)(s + i);
    u16x4 o;
    o[0] = f2b(v.x); o[1] = f2b(v.y); o[2] = f2b(v.z); o[3] = f2b(v.w);
    *(u16x4*)(d + i) = o;
}

// XCD-aware bijective swizzle of linear wg id (nwg % 8 == 0)
__device__ __forceinline__ int xcd_swz(int wgid, int nwg) {
    int cpx = nwg >> 3;
    return (wgid & 7) * cpx + (wgid >> 3);
}

// ---------------- MFMA GEMM 128x256, 8 waves, double-buffered (in-proj) -------
__global__ __launch_bounds__(512) void mgemm_w(const ushort_t* __restrict__ A,
    const ushort_t* __restrict__ Bt, ushort_t* __restrict__ Cb,
    int M, int N, int K, int lda, int ldb)
{
    __shared__ ushort_t sA[2][128 * 32];
    __shared__ ushort_t sB[2][256 * 32];
    const int tid = threadIdx.x;
    const int lane = tid & 63, wv = tid >> 6;
    const int wm = wv >> 2, wn = wv & 3;                  // 2M x 4N waves
    const int swz = xcd_swz(blockIdx.y * gridDim.x + blockIdx.x, gridDim.x * gridDim.y);
    const int m0 = (swz / gridDim.x) * 128, n0 = (swz % gridDim.x) * 256;
    const int sr = tid >> 2;                              // 0..127
    const int sc = (tid & 3) * 8;
    f32x4 acc[4][4] = {};

    __builtin_amdgcn_global_load_lds(
        (const uint_t*)(A + (size_t)(m0 + sr) * lda + sc),
        (uint_t*)(sA[0] + sr * 32 + sc), 16, 0, 0);
#pragma unroll
    for (int it = 0; it < 2; ++it) {
        int rb = (tid + it * 512) >> 2;                   // 0..255
        __builtin_amdgcn_global_load_lds(
            (const uint_t*)(Bt + (size_t)(n0 + rb) * ldb + sc),
            (uint_t*)(sB[0] + rb * 32 + sc), 16, 0, 0);
    }
    __syncthreads();
    int cur = 0;
    for (int k0 = 0; k0 < K; k0 += 32) {
        if (k0 + 32 < K) {
            int nxt = cur ^ 1;
            __builtin_amdgcn_global_load_lds(
                (const uint_t*)(A + (size_t)(m0 + sr) * lda + k0 + 32 + sc),
                (uint_t*)(sA[nxt] + sr * 32 + sc), 16, 0, 0);
#pragma unroll
            for (int it = 0; it < 2; ++it) {
                int rb = (tid + it * 512) >> 2;
                __builtin_amdgcn_global_load_lds(
                    (const uint_t*)(Bt + (size_t)(n0 + rb) * ldb + k0 + 32 + sc),
                    (uint_t*)(sB[nxt] + rb * 32 + sc), 16, 0, 0);
            }
        }
        bf16x8 af[4], bfr[4];
#pragma unroll
        for (int i = 0; i < 4; ++i) {
            af[i]  = *(const bf16x8*)(sA[cur] + (wm * 64 + i * 16 + (lane & 15)) * 32 + (lane >> 4) * 8);
            bfr[i] = *(const bf16x8*)(sB[cur] + (wn * 64 + i * 16 + (lane & 15)) * 32 + (lane >> 4) * 8);
        }
#pragma unroll
        for (int i = 0; i < 4; ++i)
#pragma unroll
            for (int jj = 0; jj < 4; ++jj)
                acc[i][jj] = __builtin_amdgcn_mfma_f32_16x16x32_bf16(af[i], bfr[jj], acc[i][jj], 0, 0, 0);
        __syncthreads();
        cur ^= 1;
    }

    const int cr = (lane >> 4) * 4, cc = lane & 15;
#pragma unroll
    for (int i = 0; i < 4; ++i) {
        int mrow = m0 + wm * 64 + i * 16 + cr;
#pragma unroll
        for (int jj = 0; jj < 4; ++jj) {
            int ncol = n0 + wn * 64 + jj * 16 + cc;
#pragma unroll
            for (int r = 0; r < 4; ++r)
                Cb[(size_t)(mrow + r) * N + ncol] = f2b(acc[i][jj][r]);
        }
    }
}

// ---------------- MFMA GEMM 128x128, dbuf (dt-proj) ----------------------------
// EPI 2: bf16 Cb = softplus(C + bias[n])
__global__ __launch_bounds__(256) void mgemm_dt(const ushort_t* __restrict__ A,
    const ushort_t* __restrict__ Bt, ushort_t* __restrict__ Cb,
    const float* __restrict__ bias, int M, int N, int K, int lda, int ldb)
{
    __shared__ ushort_t sA[2][128 * 32];
    __shared__ ushort_t sB[2][128 * 32];
    const int tid = threadIdx.x;
    const int lane = tid & 63, wv = tid >> 6;
    const int wm = wv >> 1, wn = wv & 1;
    const int swz = xcd_swz(blockIdx.y * gridDim.x + blockIdx.x, gridDim.x * gridDim.y);
    const int m0 = (swz / gridDim.x) * 128, n0 = (swz % gridDim.x) * 128;
    const int sr = tid >> 2;
    const int sc = (tid & 3) * 8;
    f32x4 acc[4][4] = {};

#pragma unroll
    for (int j = 0; j < 2; ++j) {
        int ra = sr + j * 64;
        __builtin_amdgcn_global_load_lds(
            (const uint_t*)(A + (size_t)(m0 + ra) * lda + sc),
            (uint_t*)(sA[0] + ra * 32 + sc), 16, 0, 0);
        int gb = n0 + ra; if (gb >= N) gb = N - 1;
        __builtin_amdgcn_global_load_lds(
            (const uint_t*)(Bt + (size_t)gb * ldb + sc),
            (uint_t*)(sB[0] + ra * 32 + sc), 16, 0, 0);
    }
    __syncthreads();
    int cur = 0;
    for (int k0 = 0; k0 < K; k0 += 32) {
        if (k0 + 32 < K) {
            int nxt = cur ^ 1;
#pragma unroll
            for (int j = 0; j < 2; ++j) {
                int ra = sr + j * 64;
                __builtin_amdgcn_global_load_lds(
                    (const uint_t*)(A + (size_t)(m0 + ra) * lda + k0 + 32 + sc),
                    (uint_t*)(sA[nxt] + ra * 32 + sc), 16, 0, 0);
                int gb = n0 + ra; if (gb >= N) gb = N - 1;
                __builtin_amdgcn_global_load_lds(
                    (const uint_t*)(Bt + (size_t)gb * ldb + k0 + 32 + sc),
                    (uint_t*)(sB[nxt] + ra * 32 + sc), 16, 0, 0);
            }
        }
        bf16x8 af[4], bfr[4];
#pragma unroll
        for (int i = 0; i < 4; ++i) {
            af[i]  = *(const bf16x8*)(sA[cur] + (wm * 64 + i * 16 + (lane & 15)) * 32 + (lane >> 4) * 8);
            bfr[i] = *(const bf16x8*)(sB[cur] + (wn * 64 + i * 16 + (lane & 15)) * 32 + (lane >> 4) * 8);
        }
#pragma unroll
        for (int i = 0; i < 4; ++i)
#pragma unroll
            for (int jj = 0; jj < 4; ++jj)
                acc[i][jj] = __builtin_amdgcn_mfma_f32_16x16x32_bf16(af[i], bfr[jj], acc[i][jj], 0, 0, 0);
        __syncthreads();
        cur ^= 1;
    }

    const int cr = (lane >> 4) * 4, cc = lane & 15;
#pragma unroll
    for (int i = 0; i < 4; ++i) {
        int mrow = m0 + wm * 64 + i * 16 + cr;
#pragma unroll
        for (int jj = 0; jj < 4; ++jj) {
            int ncol = n0 + wn * 64 + jj * 16 + cc;
            if (ncol < N) {
#pragma unroll
                for (int r = 0; r < 4; ++r) {
                    float v = acc[i][jj][r];
                    size_t off = (size_t)(mrow + r) * N + ncol;
                    float s = v + bias[ncol];
                    Cb[off] = f2b((s > 20.f) ? s : log1pf(expf(s)));
                }
            }
        }
    }
}

// ---------------- MFMA GEMM 128xK split-K (N=96 W_x proj), dbuf ----------------
__global__ __launch_bounds__(256) void mgemm_sk(const ushort_t* __restrict__ A,
    const ushort_t* __restrict__ Bt, float* __restrict__ P,
    int M, int N, int Kslice, int lda, int ldb)
{
    __shared__ ushort_t sA[2][128 * 32];
    __shared__ ushort_t sB[2][128 * 32];
    const int tid = threadIdx.x;
    const int lane = tid & 63, wv = tid >> 6;
    const int wm = wv >> 1, wn = wv & 1;
    const int m0 = blockIdx.y * 128;
    const int kbase = blockIdx.z * Kslice;
    const int sr = tid >> 2;
    const int sc = (tid & 3) * 8;
    f32x4 acc[4][4] = {};

#pragma unroll
    for (int j = 0; j < 2; ++j) {
        int ra = sr + j * 64;
        __builtin_amdgcn_global_load_lds(
            (const uint_t*)(A + (size_t)(m0 + ra) * lda + kbase + sc),
            (uint_t*)(sA[0] + ra * 32 + sc), 16, 0, 0);
        int gb = ra; if (gb >= N) gb = N - 1;
        __builtin_amdgcn_global_load_lds(
            (const uint_t*)(Bt + (size_t)gb * ldb + kbase + sc),
            (uint_t*)(sB[0] + ra * 32 + sc), 16, 0, 0);
    }
    __syncthreads();
    int cur = 0;
    for (int k0 = kbase; k0 < kbase + Kslice; k0 += 32) {
        if (k0 + 32 < kbase + Kslice) {
            int nxt = cur ^ 1;
#pragma unroll
            for (int j = 0; j < 2; ++j) {
                int ra = sr + j * 64;
                __builtin_amdgcn_global_load_lds(
                    (const uint_t*)(A + (size_t)(m0 + ra) * lda + k0 + 32 + sc),
                    (uint_t*)(sA[nxt] + ra * 32 + sc), 16, 0, 0);
                int gb = ra; if (gb >= N) gb = N - 1;
                __builtin_amdgcn_global_load_lds(
                    (const uint_t*)(Bt + (size_t)gb * ldb + k0 + 32 + sc),
                    (uint_t*)(sB[nxt] + ra * 32 + sc), 16, 0, 0);
            }
        }
        bf16x8 af[4], bfr[4];
#pragma unroll
        for (int i = 0; i < 4; ++i) {
            af[i]  = *(const bf16x8*)(sA[cur] + (wm * 64 + i * 16 + (lane & 15)) * 32 + (lane >> 4) * 8);
            bfr[i] = *(const bf16x8*)(sB[cur] + (wn * 64 + i * 16 + (lane & 15)) * 32 + (lane >> 4) * 8);
        }
#pragma unroll
        for (int i = 0; i < 4; ++i)
#pragma unroll
            for (int jj = 0; jj < 4; ++jj)
                acc[i][jj] = __builtin_amdgcn_mfma_f32_16x16x32_bf16(af[i], bfr[jj], acc[i][jj], 0, 0, 0);
        __syncthreads();
        cur ^= 1;
    }

    const int cr = (lane >> 4) * 4, cc = lane & 15;
    float* Pz = P + (size_t)blockIdx.z * M * 96;
#pragma unroll
    for (int i = 0; i < 4; ++i) {
        int mrow = m0 + wm * 64 + i * 16 + cr;
#pragma unroll
        for (int jj = 0; jj < 4; ++jj) {
            int ncol = wn * 64 + jj * 16 + cc;
            if (ncol < 96) {
#pragma unroll
                for (int r = 0; r < 4; ++r)
                    Pz[(size_t)(mrow + r) * 96 + ncol] = acc[i][jj][r];
            }
        }
    }
}

// reduce split-K partials -> xdbl f32 + xdblb bf16
__global__ __launch_bounds__(256) void wxred_k(const float* __restrict__ P,
    float* __restrict__ xdbl, ushort_t* __restrict__ xdblb)
{
    int idx = blockIdx.x * 256 + threadIdx.x;
    float s = 0.f;
#pragma unroll
    for (int z = 0; z < 8; ++z) s += P[(size_t)z * 196608 + idx];
    xdbl[idx] = s;
    xdblb[idx] = f2b(s);
}

// ---------------- MFMA GEMM 128x64 (N=1024 out-proj), dbuf ---------------------
// EPI: 3 = bf16 only; 4 = f32 C = acc + res
template<int EPI>
__global__ __launch_bounds__(256) void mgemm_n64(const ushort_t* __restrict__ A,
    const ushort_t* __restrict__ Bt, float* __restrict__ Cf, ushort_t* __restrict__ Cb,
    const float* __restrict__ res, int M, int N, int K, int lda, int ldb)
{
    __shared__ ushort_t sA[2][128 * 32];
    __shared__ ushort_t sB[2][64 * 32];
    const int tid = threadIdx.x;
    const int lane = tid & 63, wv = tid >> 6;
    const int swz = xcd_swz(blockIdx.y * gridDim.x + blockIdx.x, gridDim.x * gridDim.y);
    const int m0 = (swz / gridDim.x) * 128, n0 = (swz % gridDim.x) * 64;
    const int sr = tid >> 2;
    const int sc = (tid & 3) * 8;
    f32x4 acc[2][4] = {};

#pragma unroll
    for (int j = 0; j < 2; ++j) {
        int ra = sr + j * 64;
        __builtin_amdgcn_global_load_lds(
            (const uint_t*)(A + (size_t)(m0 + ra) * lda + sc),
            (uint_t*)(sA[0] + ra * 32 + sc), 16, 0, 0);
    }
    __builtin_amdgcn_global_load_lds(
        (const uint_t*)(Bt + (size_t)(n0 + sr) * ldb + sc),
        (uint_t*)(sB[0] + sr * 32 + sc), 16, 0, 0);
    __syncthreads();
    int cur = 0;
    for (int k0 = 0; k0 < K; k0 += 32) {
        if (k0 + 32 < K) {
            int nxt = cur ^ 1;
#pragma unroll
            for (int j = 0; j < 2; ++j) {
                int ra = sr + j * 64;
                __builtin_amdgcn_global_load_lds(
                    (const uint_t*)(A + (size_t)(m0 + ra) * lda + k0 + 32 + sc),
                    (uint_t*)(sA[nxt] + ra * 32 + sc), 16, 0, 0);
            }
            __builtin_amdgcn_global_load_lds(
                (const uint_t*)(Bt + (size_t)(n0 + sr) * ldb + k0 + 32 + sc),
                (uint_t*)(sB[nxt] + sr * 32 + sc), 16, 0, 0);
        }
        bf16x8 af[2], bfr[4];
#pragma unroll
        for (int i = 0; i < 2; ++i)
            af[i]  = *(const bf16x8*)(sA[cur] + (wv * 32 + i * 16 + (lane & 15)) * 32 + (lane >> 4) * 8);
#pragma unroll
        for (int jj = 0; jj < 4; ++jj)
            bfr[jj] = *(const bf16x8*)(sB[cur] + (jj * 16 + (lane & 15)) * 32 + (lane >> 4) * 8);
#pragma unroll
        for (int i = 0; i < 2; ++i)
#pragma unroll
            for (int jj = 0; jj < 4; ++jj)
                acc[i][jj] = __builtin_amdgcn_mfma_f32_16x16x32_bf16(af[i], bfr[jj], acc[i][jj], 0, 0, 0);
        __syncthreads();
        cur ^= 1;
    }

    const int cr = (lane >> 4) * 4, cc = lane & 15;
#pragma unroll
    for (int i = 0; i < 2; ++i) {
        int mrow = m0 + wv * 32 + i * 16 + cr;
#pragma unroll
        for (int jj = 0; jj < 4; ++jj) {
            int ncol = n0 + jj * 16 + cc;
#pragma unroll
            for (int r = 0; r < 4; ++r) {
                float v = acc[i][jj][r];
                size_t off = (size_t)(mrow + r) * N + ncol;
                if (EPI == 3) Cb[off] = f2b(v);
                else Cf[off] = v + res[off];
            }
        }
    }
}

// conv + silu, 8 channels per thread
__global__ __launch_bounds__(256) void conv8_k(const ushort_t* __restrict__ xzb,
    const float* __restrict__ cw, const float* __restrict__ cb,
    ushort_t* __restrict__ ucb)
{
    int idx8 = blockIdx.x * 256 + threadIdx.x;
    int d8 = (idx8 & 255) * 8;
    int t = (idx8 >> 8) & (L_ - 1);
    int b = idx8 >> 18;
    const ushort_t* base = xzb + (size_t)b * L_ * (2 * DIN) + d8;
    float acc[8];
    const float4* cb4 = (const float4*)(cb + d8);
    float4 cbl = cb4[0], cbh = cb4[1];
#pragma unroll
    for (int e = 0; e < 4; ++e) { acc[e] = ((const float*)&cbl)[e]; acc[4 + e] = ((const float*)&cbh)[e]; }
    float4 cwv[8];
#pragma unroll
    for (int e = 0; e < 8; ++e) cwv[e] = ((const float4*)cw)[d8 + e];
#pragma unroll
    for (int j = 0; j < 4; ++j) {
        int tt = t - 3 + j;
        if (tt >= 0) {
            u16x8 row = *(const u16x8*)(base + (size_t)tt * (2 * DIN));
#pragma unroll
            for (int e = 0; e < 8; ++e)
                acc[e] = fmaf(((const float*)&cwv[e])[j], b2f(row[e]), acc[e]);
        }
    }
    u16x8 ob;
#pragma unroll
    for (int e = 0; e < 8; ++e) {
        float v = acc[e] * sigmoidf_(acc[e]);
        ob[e] = f2b(v);
    }
    *(u16x8*)(ucb + (size_t)idx8 * 8) = ob;
}

// ---------------- chunk-parallel scan, 16 states per THREAD -------------------
// S1: local scan from zero -> bnd_q[(b,c,d),n], bnd_s[(b,c,d)]
__global__ __launch_bounds__(256, 2) void scan_s1(const ushort_t* __restrict__ dtfb,
    const ushort_t* __restrict__ ucb, const float* __restrict__ xdbl,
    const float* __restrict__ A_log,
    float* __restrict__ bnd_q, float* __restrict__ bnd_s)
{
    __shared__ uint_t sdt[CHL * 256];
    __shared__ float sB[CHL * 16];
    const int tid = threadIdx.x;
    const int bx = blockIdx.x;
    const int dg = bx & 7, c = (bx >> 3) & 31, b = bx >> 8;
    const int d = dg * 256 + tid;
    const int row0 = b * L_ + c * CHL;

    float A_dn[16];
#pragma unroll
    for (int n = 0; n < 16; ++n) A_dn[n] = -__expf(A_log[(size_t)d * DS + n]);

    for (int k = 0; k < CHL; ++k) {
        size_t off = (size_t)(row0 + k) * DIN + d;
        sdt[k * 256 + tid] = (uint_t)dtfb[off] | ((uint_t)ucb[off] << 16);
    }
#pragma unroll
    for (int j = 0; j < 2; ++j) {
        int idx = tid + j * 256;
        int t = idx >> 4, n = idx & 15;
        sB[idx] = xdbl[(size_t)(row0 + t) * 96 + 64 + n];
    }
    __syncthreads();

    float q[16];
#pragma unroll
    for (int n = 0; n < 16; ++n) q[n] = 0.f;
    float s = 0.f;
    for (int k = 0; k < CHL; ++k) {
        uint_t pk = sdt[k * 256 + tid];
        float dtv = __uint_as_float(pk << 16);
        float uv  = __uint_as_float(pk & 0xffff0000u);
        float dtu = dtv * uv;
        s += dtv;
        f32x4 Bq[4];
#pragma unroll
        for (int j = 0; j < 4; ++j) Bq[j] = *(const f32x4*)(sB + k * 16 + j * 4);
#pragma unroll
        for (int n = 0; n < 16; ++n)
            q[n] = fmaf(__expf(dtv * A_dn[n]), q[n], dtu * Bq[n >> 2][n & 3]);
    }
    float* qp = bnd_q + ((size_t)(b * NCH + c) * DIN + d) * 16;
#pragma unroll
    for (int j = 0; j < 4; ++j)
        *(f32x4*)(qp + j * 4) = (f32x4){q[j * 4], q[j * 4 + 1], q[j * 4 + 2], q[j * 4 + 3]};
    bnd_s[(size_t)(b * NCH + c) * DIN + d] = s;
}

// S2: inline boundary combine from bnd -> rescan chunk -> gate -> store (in loop)
__global__ __launch_bounds__(256, 2) void scan_s2(const ushort_t* __restrict__ dtfb,
    const ushort_t* __restrict__ ucb_in, const float* __restrict__ xdbl,
    const ushort_t* __restrict__ xzb, const float* __restrict__ A_log,
    const float* __restrict__ Dvec, const float* __restrict__ bnd_q,
    const float* __restrict__ bnd_s, ushort_t* __restrict__ ucb_out)
{
    __shared__ uint_t sdt[CHL * 256];
    __shared__ float sBC[CHL * 32];
    const int tid = threadIdx.x;
    const int bx = blockIdx.x;
    const int dg = bx & 7, c = (bx >> 3) & 31, b = bx >> 8;
    const int d = dg * 256 + tid;
    const int row0 = b * L_ + c * CHL;
    const float Dd = Dvec[d];

    float A_dn[16];
#pragma unroll
    for (int n = 0; n < 16; ++n) A_dn[n] = -__expf(A_log[(size_t)d * DS + n]);

    for (int k = 0; k < CHL; ++k) {
        size_t off = (size_t)(row0 + k) * DIN + d;
        sdt[k * 256 + tid] = (uint_t)dtfb[off] | ((uint_t)ucb_in[off] << 16);
    }
#pragma unroll
    for (int j = 0; j < 4; ++j) {
        int idx = tid + j * 256;
        int t = idx >> 5, jj = idx & 31;
        sBC[idx] = xdbl[(size_t)(row0 + t) * 96 + 64 + (jj & 1) * 16 + (jj >> 1)];
    }

    // inline boundary combine: H before chunk c
    float h[16];
#pragma unroll
    for (int n = 0; n < 16; ++n) h[n] = 0.f;
    const size_t cb_base = (size_t)b * NCH * DIN + d;
    for (int cc = 0; cc < c; ++cc) {
        size_t idx = cb_base + (size_t)cc * DIN;
        float sv = bnd_s[idx];
        const float* qp = bnd_q + idx * 16;
        f32x4 qv[4];
#pragma unroll
        for (int j = 0; j < 4; ++j) qv[j] = *(const f32x4*)(qp + j * 4);
#pragma unroll
        for (int n = 0; n < 16; ++n)
            h[n] = fmaf(__expf(A_dn[n] * sv), h[n], qv[n >> 2][n & 3]);
    }
    __syncthreads();

    for (int k = 0; k < CHL; ++k) {
        uint_t pk = sdt[k * 256 + tid];
        float dtv = __uint_as_float(pk << 16);
        float uv  = __uint_as_float(pk & 0xffff0000u);
        float dtu = dtv * uv;
        float z = b2f(xzb[(size_t)(row0 + k) * (2 * DIN) + DIN + d]);
        float y = uv * Dd;
        f32x4 bcq[8];
#pragma unroll
        for (int j = 0; j < 8; ++j) bcq[j] = *(const f32x4*)(sBC + k * 32 + j * 4);
#pragma unroll
        for (int n = 0; n < 16; ++n) {
            float Bv = bcq[n >> 1][(n & 1) * 2];
            float Cv = bcq[n >> 1][(n & 1) * 2 + 1];
            h[n] = fmaf(__expf(dtv * A_dn[n]), h[n], dtu * Bv);
            y = fmaf(h[n], Cv, y);
        }
        y *= z * sigmoidf_(z);
        ucb_out[(size_t)(row0 + k) * DIN + d] = f2b(y);
    }
}

extern "C" void kernel_launch(void* const* d_in, const int* in_sizes, int n_in,
                              void* d_out, int out_size, void* d_ws, size_t ws_size,
                              hipStream_t stream)
{
    (void)in_sizes; (void)n_in; (void)out_size; (void)ws_size;
    const float* x      = (const float*)d_in[0];
    const float* W_in   = (const float*)d_in[1];
    const float* conv_w = (const float*)d_in[2];
    const float* conv_b = (const float*)d_in[3];
    const float* W_x    = (const float*)d_in[4];
    const float* W_dt   = (const float*)d_in[5];
    const float* b_dt   = (const float*)d_in[6];
    const float* A_log  = (const float*)d_in[7];
    const float* Dv     = (const float*)d_in[8];
    const float* W_out  = (const float*)d_in[9];
    float* out = (float*)d_out;

    // workspace layout
    float* xdbl    = (float*)d_ws;                       //   196,608 f32
    float* pws     = xdbl + 196608;                      // 1,572,864 f32
    float* bnd_q   = pws + 1572864;                      // 2,097,152 f32
    float* bnd_s   = bnd_q + 2097152;                    //   131,072 f32
    ushort_t* dtfb = (ushort_t*)(bnd_s + 131072);        // 4,194,304 u16
    ushort_t* xzb  = dtfb + 4194304;                     // 8,388,608
    ushort_t* ucb  = xzb + 8388608;                      // 4,194,304
    ushort_t* xdblb= ucb + 4194304;                      //   196,608
    ushort_t* xb   = xdblb + 196608;                     // 2,097,152 (x/h bf16)
    ushort_t* wib  = xb + 2097152;                       // 8,388,608
    ushort_t* wxb  = wib + 8388608;                      //   393,216
    ushort_t* wdb  = wxb + 393216;                       //   262,144
    ushort_t* wob  = wdb + 262144;                       // 4,194,304

    const int M = B_ * L_;
    const int NT = 2097152 + 8388608 + 393216 + 262144 + 4194304;
    f2b_all_k<<<(NT / 4) / 256, 256, 0, stream>>>(
        x, xb, 2097152, W_in, wib, 8388608, W_x, wxb, 393216,
        W_dt, wdb, 262144, W_out, wob, 4194304);

    for (int layer = 0; layer < 2; ++layer) {
        // xzb = bf16( h @ W_in^T )  [M, 4096] — 128x256 8-wave kernel
        mgemm_w<<<dim3(4096 / 256, M / 128), 512, 0, stream>>>(
            xb, wib + (size_t)layer * 4194304, xzb, M, 2 * DIN, DM, DM, DM);
        // ucb = bf16(silu(conv(u) + b))
        conv8_k<<<(B_ * L_ * DIN / 8) / 256, 256, 0, stream>>>(
            xzb, conv_w + (size_t)layer * DIN * 4, conv_b + (size_t)layer * DIN, ucb);
        // xdbl = uc @ W_x^T  [M, 96]  (split-K x8 + reduce)
        mgemm_sk<<<dim3(1, M / 128, 8), 256, 0, stream>>>(
            ucb, wxb + (size_t)layer * 196608, pws, M, 96, DIN / 8, DIN, DIN);
        wxred_k<<<196608 / 256, 256, 0, stream>>>(pws, xdbl, xdblb);
        // dtfb = bf16(softplus(xdblb[:, :64] @ W_dt^T + b_dt))  [M, 2048]
        mgemm_dt<<<dim3(2048 / 128, M / 128), 256, 0, stream>>>(
            xdblb, wdb + (size_t)layer * 131072, dtfb,
            b_dt + (size_t)layer * DIN, M, DIN, DTR, 96, DTR);
        // chunk-parallel scan (two kernels; cooperative launch crashed the harness)
        const float* Al = A_log + (size_t)layer * DIN * DS;
        scan_s1<<<B_ * NCH * 8, 256, 0, stream>>>(dtfb, ucb, xdbl, Al, bnd_q, bnd_s);
        scan_s2<<<B_ * NCH * 8, 256, 0, stream>>>(dtfb, ucb, xdbl, xzb, Al,
            Dv + (size_t)layer * DIN, bnd_q, bnd_s, ucb);
        // out-proj (128x64 tiles): layer0 -> xb (bf16 h); layer1 -> out = acc + x
        if (layer == 0)
            mgemm_n64<3><<<dim3(1024 / 64, M / 128), 256, 0, stream>>>(
                ucb, wob + (size_t)layer * 2097152, nullptr, xb, nullptr,
                M, DM, DIN, DIN, DIN);
        else
            mgemm_n64<4><<<dim3(1024 / 64, M / 128), 256, 0, stream>>>(
                ucb, wob + (size_t)layer * 2097152, out, nullptr, x,
                M, DM, DIN, DIN, DIN);
    }
}

// Round 10
// 451.087 us; speedup vs baseline: 1.0127x; 1.0127x over previous
//
#include <hip/hip_runtime.h>
#include <hip/hip_bf16.h>
#include <math.h>

#define B_ 2
#define L_ 1024
#define DM 1024
#define DIN 2048
#define DS 16
#define DTR 64
#define CHL 32      // chunk length
#define NCH 32      // chunks per sequence

typedef __attribute__((ext_vector_type(8))) short bf16x8;
typedef __attribute__((ext_vector_type(8))) unsigned short u16x8;
typedef __attribute__((ext_vector_type(4))) unsigned short u16x4;
typedef __attribute__((ext_vector_type(4))) float f32x4;
typedef unsigned short ushort_t;
typedef unsigned int uint_t;

__device__ __forceinline__ float sigmoidf_(float x) { return 1.f / (1.f + __expf(-x)); }
__device__ __forceinline__ ushort_t f2b(float f) {
    uint_t b = __float_as_uint(f);
    return (ushort_t)((b + 0x7FFFu + ((b >> 16) & 1u)) >> 16);
}
__device__ __forceinline__ float b2f(ushort_t u) {
    return __uint_as_float(((uint_t)u) << 16);
}

// fused f32 -> bf16 (RTN), 4 elems/thread
__global__ __launch_bounds__(256) void f2b_all_k(
    const float* __restrict__ s0, ushort_t* __restrict__ d0, int n0,
    const float* __restrict__ s1, ushort_t* __restrict__ d1, int n1,
    const float* __restrict__ s2, ushort_t* __restrict__ d2, int n2,
    const float* __restrict__ s3, ushort_t* __restrict__ d3, int n3,
    const float* __restrict__ s4, ushort_t* __restrict__ d4, int n4)
{
    int i = (blockIdx.x * 256 + threadIdx.x) * 4;
    const float* s; ushort_t* d;
    if (i < n0) { s = s0; d = d0; }
    else { i -= n0;
    if (i < n1) { s = s1; d = d1; }
    else { i -= n1;
    if (i < n2) { s = s2; d = d2; }
    else { i -= n2;
    if (i < n3) { s = s3; d = d3; }
    else { i -= n3;
    if (i < n4) { s = s4; d = d4; }
    else return; }}}}
    float4 v = *(const float4*)(s + i);
    u16x4 o;
    o[0] = f2b(v.x); o[1] = f2b(v.y); o[2] = f2b(v.z); o[3] = f2b(v.w);
    *(u16x4*)(d + i) = o;
}

// XCD-aware bijective swizzle of linear wg id (nwg % 8 == 0)
__device__ __forceinline__ int xcd_swz(int wgid, int nwg) {
    int cpx = nwg >> 3;
    return (wgid & 7) * cpx + (wgid >> 3);
}

// ---------------- MFMA GEMM 128x128, dbuf (in-proj), bf16 out ------------------
__global__ __launch_bounds__(256) void mgemm_in(const ushort_t* __restrict__ A,
    const ushort_t* __restrict__ Bt, ushort_t* __restrict__ Cb,
    int M, int N, int K, int lda, int ldb)
{
    __shared__ ushort_t sA[2][128 * 32];
    __shared__ ushort_t sB[2][128 * 32];
    const int tid = threadIdx.x;
    const int lane = tid & 63, wv = tid >> 6;
    const int wm = wv >> 1, wn = wv & 1;
    const int swz = xcd_swz(blockIdx.y * gridDim.x + blockIdx.x, gridDim.x * gridDim.y);
    const int m0 = (swz / gridDim.x) * 128, n0 = (swz % gridDim.x) * 128;
    const int sr = tid >> 2;
    const int sc = (tid & 3) * 8;
    f32x4 acc[4][4] = {};

#pragma unroll
    for (int j = 0; j < 2; ++j) {
        int ra = sr + j * 64;
        __builtin_amdgcn_global_load_lds(
            (const uint_t*)(A + (size_t)(m0 + ra) * lda + sc),
            (uint_t*)(sA[0] + ra * 32 + sc), 16, 0, 0);
        __builtin_amdgcn_global_load_lds(
            (const uint_t*)(Bt + (size_t)(n0 + ra) * ldb + sc),
            (uint_t*)(sB[0] + ra * 32 + sc), 16, 0, 0);
    }
    __syncthreads();
    int cur = 0;
    for (int k0 = 0; k0 < K; k0 += 32) {
        if (k0 + 32 < K) {
            int nxt = cur ^ 1;
#pragma unroll
            for (int j = 0; j < 2; ++j) {
                int ra = sr + j * 64;
                __builtin_amdgcn_global_load_lds(
                    (const uint_t*)(A + (size_t)(m0 + ra) * lda + k0 + 32 + sc),
                    (uint_t*)(sA[nxt] + ra * 32 + sc), 16, 0, 0);
                __builtin_amdgcn_global_load_lds(
                    (const uint_t*)(Bt + (size_t)(n0 + ra) * ldb + k0 + 32 + sc),
                    (uint_t*)(sB[nxt] + ra * 32 + sc), 16, 0, 0);
            }
        }
        bf16x8 af[4], bfr[4];
#pragma unroll
        for (int i = 0; i < 4; ++i) {
            af[i]  = *(const bf16x8*)(sA[cur] + (wm * 64 + i * 16 + (lane & 15)) * 32 + (lane >> 4) * 8);
            bfr[i] = *(const bf16x8*)(sB[cur] + (wn * 64 + i * 16 + (lane & 15)) * 32 + (lane >> 4) * 8);
        }
#pragma unroll
        for (int i = 0; i < 4; ++i)
#pragma unroll
            for (int jj = 0; jj < 4; ++jj)
                acc[i][jj] = __builtin_amdgcn_mfma_f32_16x16x32_bf16(af[i], bfr[jj], acc[i][jj], 0, 0, 0);
        __syncthreads();
        cur ^= 1;
    }

    const int cr = (lane >> 4) * 4, cc = lane & 15;
#pragma unroll
    for (int i = 0; i < 4; ++i) {
        int mrow = m0 + wm * 64 + i * 16 + cr;
#pragma unroll
        for (int jj = 0; jj < 4; ++jj) {
            int ncol = n0 + wn * 64 + jj * 16 + cc;
#pragma unroll
            for (int r = 0; r < 4; ++r)
                Cb[(size_t)(mrow + r) * N + ncol] = f2b(acc[i][jj][r]);
        }
    }
}

// ---------------- MFMA GEMM 128xK split-K (N=96 W_x proj), dbuf ----------------
__global__ __launch_bounds__(256) void mgemm_sk(const ushort_t* __restrict__ A,
    const ushort_t* __restrict__ Bt, float* __restrict__ P,
    int M, int N, int Kslice, int lda, int ldb)
{
    __shared__ ushort_t sA[2][128 * 32];
    __shared__ ushort_t sB[2][128 * 32];
    const int tid = threadIdx.x;
    const int lane = tid & 63, wv = tid >> 6;
    const int wm = wv >> 1, wn = wv & 1;
    const int m0 = blockIdx.y * 128;
    const int kbase = blockIdx.z * Kslice;
    const int sr = tid >> 2;
    const int sc = (tid & 3) * 8;
    f32x4 acc[4][4] = {};

#pragma unroll
    for (int j = 0; j < 2; ++j) {
        int ra = sr + j * 64;
        __builtin_amdgcn_global_load_lds(
            (const uint_t*)(A + (size_t)(m0 + ra) * lda + kbase + sc),
            (uint_t*)(sA[0] + ra * 32 + sc), 16, 0, 0);
        int gb = ra; if (gb >= N) gb = N - 1;
        __builtin_amdgcn_global_load_lds(
            (const uint_t*)(Bt + (size_t)gb * ldb + kbase + sc),
            (uint_t*)(sB[0] + ra * 32 + sc), 16, 0, 0);
    }
    __syncthreads();
    int cur = 0;
    for (int k0 = kbase; k0 < kbase + Kslice; k0 += 32) {
        if (k0 + 32 < kbase + Kslice) {
            int nxt = cur ^ 1;
#pragma unroll
            for (int j = 0; j < 2; ++j) {
                int ra = sr + j * 64;
                __builtin_amdgcn_global_load_lds(
                    (const uint_t*)(A + (size_t)(m0 + ra) * lda + k0 + 32 + sc),
                    (uint_t*)(sA[nxt] + ra * 32 + sc), 16, 0, 0);
                int gb = ra; if (gb >= N) gb = N - 1;
                __builtin_amdgcn_global_load_lds(
                    (const uint_t*)(Bt + (size_t)gb * ldb + k0 + 32 + sc),
                    (uint_t*)(sB[nxt] + ra * 32 + sc), 16, 0, 0);
            }
        }
        bf16x8 af[4], bfr[4];
#pragma unroll
        for (int i = 0; i < 4; ++i) {
            af[i]  = *(const bf16x8*)(sA[cur] + (wm * 64 + i * 16 + (lane & 15)) * 32 + (lane >> 4) * 8);
            bfr[i] = *(const bf16x8*)(sB[cur] + (wn * 64 + i * 16 + (lane & 15)) * 32 + (lane >> 4) * 8);
        }
#pragma unroll
        for (int i = 0; i < 4; ++i)
#pragma unroll
            for (int jj = 0; jj < 4; ++jj)
                acc[i][jj] = __builtin_amdgcn_mfma_f32_16x16x32_bf16(af[i], bfr[jj], acc[i][jj], 0, 0, 0);
        __syncthreads();
        cur ^= 1;
    }

    const int cr = (lane >> 4) * 4, cc = lane & 15;
    float* Pz = P + (size_t)blockIdx.z * M * 96;
#pragma unroll
    for (int i = 0; i < 4; ++i) {
        int mrow = m0 + wm * 64 + i * 16 + cr;
#pragma unroll
        for (int jj = 0; jj < 4; ++jj) {
            int ncol = wn * 64 + jj * 16 + cc;
            if (ncol < 96) {
#pragma unroll
                for (int r = 0; r < 4; ++r)
                    Pz[(size_t)(mrow + r) * 96 + ncol] = acc[i][jj][r];
            }
        }
    }
}

// ---- fused: reduce split-K partials (cols 0:64 -> LDS bf16 A) + dt-proj GEMM --
// also (bx==0) reduces cols 64:96 -> xdbl f32 for the scan.
// grid (16 n-blocks, 16 m-blocks), 256 threads. K = 64 (two 32-steps).
__global__ __launch_bounds__(256) void mgemm_dtf(const float* __restrict__ P,
    const ushort_t* __restrict__ Wd, const float* __restrict__ bias,
    float* __restrict__ xdbl, ushort_t* __restrict__ dtfb)
{
    __shared__ ushort_t sA[2][128 * 36];   // pad 36/row-half: <=2-way banks
    __shared__ ushort_t sB[2][128 * 32];
    const int tid = threadIdx.x;
    const int lane = tid & 63, wv = tid >> 6;
    const int wm = wv >> 1, wn = wv & 1;
    const int n0 = blockIdx.x * 128, m0 = blockIdx.y * 128;

    // stage W_dt tile (128 rows x 64 cols) as two 32-col halves
#pragma unroll
    for (int kh = 0; kh < 2; ++kh)
#pragma unroll
        for (int it = 0; it < 2; ++it) {
            int ci = tid + it * 256;             // 0..511
            int row = ci >> 2, cc = ci & 3;
            __builtin_amdgcn_global_load_lds(
                (const uint_t*)(Wd + (size_t)(n0 + row) * 64 + kh * 32 + cc * 8),
                (uint_t*)(sB[kh] + (size_t)ci * 8), 16, 0, 0);
        }

    // sum 8 partials for cols 0:64 -> bf16 LDS A tile
#pragma unroll
    for (int it = 0; it < 8; ++it) {
        int ci = tid + it * 256;                 // 0..2047
        int row = ci >> 4, c4 = (ci & 15) * 4;
        float s0 = 0.f, s1 = 0.f, s2 = 0.f, s3 = 0.f;
#pragma unroll
        for (int z = 0; z < 8; ++z) {
            f32x4 v = *(const f32x4*)(P + (size_t)z * 196608 + (size_t)(m0 + row) * 96 + c4);
            s0 += v[0]; s1 += v[1]; s2 += v[2]; s3 += v[3];
        }
        u16x4 o; o[0] = f2b(s0); o[1] = f2b(s1); o[2] = f2b(s2); o[3] = f2b(s3);
        int kh = c4 >> 5, cl = c4 & 31;
        *(u16x4*)(sA[kh] + row * 36 + cl) = o;
    }
    // bx==0 blocks: reduce cols 64:96 -> xdbl f32 (consumed by the scan)
    if (blockIdx.x == 0) {
#pragma unroll
        for (int it = 0; it < 4; ++it) {
            int ci = tid + it * 256;             // 0..1023
            int row = ci >> 3, c4 = (ci & 7) * 4;
            f32x4 s = {0.f, 0.f, 0.f, 0.f};
#pragma unroll
            for (int z = 0; z < 8; ++z) {
                f32x4 v = *(const f32x4*)(P + (size_t)z * 196608 + (size_t)(m0 + row) * 96 + 64 + c4);
                s[0] += v[0]; s[1] += v[1]; s[2] += v[2]; s[3] += v[3];
            }
            *(f32x4*)(xdbl + (size_t)(m0 + row) * 96 + 64 + c4) = s;
        }
    }
    __syncthreads();

    f32x4 acc[4][4] = {};
#pragma unroll
    for (int ks = 0; ks < 2; ++ks) {
        bf16x8 af[4], bfr[4];
#pragma unroll
        for (int i = 0; i < 4; ++i) {
            af[i]  = *(const bf16x8*)(sA[ks] + (wm * 64 + i * 16 + (lane & 15)) * 36 + (lane >> 4) * 8);
            bfr[i] = *(const bf16x8*)(sB[ks] + (wn * 64 + i * 16 + (lane & 15)) * 32 + (lane >> 4) * 8);
        }
#pragma unroll
        for (int i = 0; i < 4; ++i)
#pragma unroll
            for (int jj = 0; jj < 4; ++jj)
                acc[i][jj] = __builtin_amdgcn_mfma_f32_16x16x32_bf16(af[i], bfr[jj], acc[i][jj], 0, 0, 0);
    }

    const int cr = (lane >> 4) * 4, cc = lane & 15;
#pragma unroll
    for (int i = 0; i < 4; ++i) {
        int mrow = m0 + wm * 64 + i * 16 + cr;
#pragma unroll
        for (int jj = 0; jj < 4; ++jj) {
            int ncol = n0 + wn * 64 + jj * 16 + cc;
#pragma unroll
            for (int r = 0; r < 4; ++r) {
                float s = acc[i][jj][r] + bias[ncol];
                dtfb[(size_t)(mrow + r) * DIN + ncol] =
                    f2b((s > 20.f) ? s : log1pf(expf(s)));
            }
        }
    }
}

// ---------------- MFMA GEMM 128x64 (N=1024 out-proj), dbuf ---------------------
// EPI: 3 = bf16 only; 4 = f32 C = acc + res
template<int EPI>
__global__ __launch_bounds__(256) void mgemm_n64(const ushort_t* __restrict__ A,
    const ushort_t* __restrict__ Bt, float* __restrict__ Cf, ushort_t* __restrict__ Cb,
    const float* __restrict__ res, int M, int N, int K, int lda, int ldb)
{
    __shared__ ushort_t sA[2][128 * 32];
    __shared__ ushort_t sB[2][64 * 32];
    const int tid = threadIdx.x;
    const int lane = tid & 63, wv = tid >> 6;
    const int swz = xcd_swz(blockIdx.y * gridDim.x + blockIdx.x, gridDim.x * gridDim.y);
    const int m0 = (swz / gridDim.x) * 128, n0 = (swz % gridDim.x) * 64;
    const int sr = tid >> 2;
    const int sc = (tid & 3) * 8;
    f32x4 acc[2][4] = {};

#pragma unroll
    for (int j = 0; j < 2; ++j) {
        int ra = sr + j * 64;
        __builtin_amdgcn_global_load_lds(
            (const uint_t*)(A + (size_t)(m0 + ra) * lda + sc),
            (uint_t*)(sA[0] + ra * 32 + sc), 16, 0, 0);
    }
    __builtin_amdgcn_global_load_lds(
        (const uint_t*)(Bt + (size_t)(n0 + sr) * ldb + sc),
        (uint_t*)(sB[0] + sr * 32 + sc), 16, 0, 0);
    __syncthreads();
    int cur = 0;
    for (int k0 = 0; k0 < K; k0 += 32) {
        if (k0 + 32 < K) {
            int nxt = cur ^ 1;
#pragma unroll
            for (int j = 0; j < 2; ++j) {
                int ra = sr + j * 64;
                __builtin_amdgcn_global_load_lds(
                    (const uint_t*)(A + (size_t)(m0 + ra) * lda + k0 + 32 + sc),
                    (uint_t*)(sA[nxt] + ra * 32 + sc), 16, 0, 0);
            }
            __builtin_amdgcn_global_load_lds(
                (const uint_t*)(Bt + (size_t)(n0 + sr) * ldb + k0 + 32 + sc),
                (uint_t*)(sB[nxt] + sr * 32 + sc), 16, 0, 0);
        }
        bf16x8 af[2], bfr[4];
#pragma unroll
        for (int i = 0; i < 2; ++i)
            af[i]  = *(const bf16x8*)(sA[cur] + (wv * 32 + i * 16 + (lane & 15)) * 32 + (lane >> 4) * 8);
#pragma unroll
        for (int jj = 0; jj < 4; ++jj)
            bfr[jj] = *(const bf16x8*)(sB[cur] + (jj * 16 + (lane & 15)) * 32 + (lane >> 4) * 8);
#pragma unroll
        for (int i = 0; i < 2; ++i)
#pragma unroll
            for (int jj = 0; jj < 4; ++jj)
                acc[i][jj] = __builtin_amdgcn_mfma_f32_16x16x32_bf16(af[i], bfr[jj], acc[i][jj], 0, 0, 0);
        __syncthreads();
        cur ^= 1;
    }

    const int cr = (lane >> 4) * 4, cc = lane & 15;
#pragma unroll
    for (int i = 0; i < 2; ++i) {
        int mrow = m0 + wv * 32 + i * 16 + cr;
#pragma unroll
        for (int jj = 0; jj < 4; ++jj) {
            int ncol = n0 + jj * 16 + cc;
#pragma unroll
            for (int r = 0; r < 4; ++r) {
                float v = acc[i][jj][r];
                size_t off = (size_t)(mrow + r) * N + ncol;
                if (EPI == 3) Cb[off] = f2b(v);
                else Cf[off] = v + res[off];
            }
        }
    }
}

// conv + silu, 8 channels per thread
__global__ __launch_bounds__(256) void conv8_k(const ushort_t* __restrict__ xzb,
    const float* __restrict__ cw, const float* __restrict__ cb,
    ushort_t* __restrict__ ucb)
{
    int idx8 = blockIdx.x * 256 + threadIdx.x;
    int d8 = (idx8 & 255) * 8;
    int t = (idx8 >> 8) & (L_ - 1);
    int b = idx8 >> 18;
    const ushort_t* base = xzb + (size_t)b * L_ * (2 * DIN) + d8;
    float acc[8];
    const float4* cb4 = (const float4*)(cb + d8);
    float4 cbl = cb4[0], cbh = cb4[1];
#pragma unroll
    for (int e = 0; e < 4; ++e) { acc[e] = ((const float*)&cbl)[e]; acc[4 + e] = ((const float*)&cbh)[e]; }
    float4 cwv[8];
#pragma unroll
    for (int e = 0; e < 8; ++e) cwv[e] = ((const float4*)cw)[d8 + e];
#pragma unroll
    for (int j = 0; j < 4; ++j) {
        int tt = t - 3 + j;
        if (tt >= 0) {
            u16x8 row = *(const u16x8*)(base + (size_t)tt * (2 * DIN));
#pragma unroll
            for (int e = 0; e < 8; ++e)
                acc[e] = fmaf(((const float*)&cwv[e])[j], b2f(row[e]), acc[e]);
        }
    }
    u16x8 ob;
#pragma unroll
    for (int e = 0; e < 8; ++e) {
        float v = acc[e] * sigmoidf_(acc[e]);
        ob[e] = f2b(v);
    }
    *(u16x8*)(ucb + (size_t)idx8 * 8) = ob;
}

// ---------------- chunk-parallel scan, 16 states per THREAD -------------------
__global__ __launch_bounds__(256, 2) void scan_s1(const ushort_t* __restrict__ dtfb,
    const ushort_t* __restrict__ ucb, const float* __restrict__ xdbl,
    const float* __restrict__ A_log,
    float* __restrict__ bnd_q, float* __restrict__ bnd_s)
{
    __shared__ uint_t sdt[CHL * 256];
    __shared__ float sB[CHL * 16];
    const int tid = threadIdx.x;
    const int bx = blockIdx.x;
    const int dg = bx & 7, c = (bx >> 3) & 31, b = bx >> 8;
    const int d = dg * 256 + tid;
    const int row0 = b * L_ + c * CHL;

    float A_dn[16];
#pragma unroll
    for (int n = 0; n < 16; ++n) A_dn[n] = -__expf(A_log[(size_t)d * DS + n]);

    for (int k = 0; k < CHL; ++k) {
        size_t off = (size_t)(row0 + k) * DIN + d;
        sdt[k * 256 + tid] = (uint_t)dtfb[off] | ((uint_t)ucb[off] << 16);
    }
#pragma unroll
    for (int j = 0; j < 2; ++j) {
        int idx = tid + j * 256;
        int t = idx >> 4, n = idx & 15;
        sB[idx] = xdbl[(size_t)(row0 + t) * 96 + 64 + n];
    }
    __syncthreads();

    float q[16];
#pragma unroll
    for (int n = 0; n < 16; ++n) q[n] = 0.f;
    float s = 0.f;
    for (int k = 0; k < CHL; ++k) {
        uint_t pk = sdt[k * 256 + tid];
        float dtv = __uint_as_float(pk << 16);
        float uv  = __uint_as_float(pk & 0xffff0000u);
        float dtu = dtv * uv;
        s += dtv;
        f32x4 Bq[4];
#pragma unroll
        for (int j = 0; j < 4; ++j) Bq[j] = *(const f32x4*)(sB + k * 16 + j * 4);
#pragma unroll
        for (int n = 0; n < 16; ++n)
            q[n] = fmaf(__expf(dtv * A_dn[n]), q[n], dtu * Bq[n >> 2][n & 3]);
    }
    float* qp = bnd_q + ((size_t)(b * NCH + c) * DIN + d) * 16;
#pragma unroll
    for (int j = 0; j < 4; ++j)
        *(f32x4*)(qp + j * 4) = (f32x4){q[j * 4], q[j * 4 + 1], q[j * 4 + 2], q[j * 4 + 3]};
    bnd_s[(size_t)(b * NCH + c) * DIN + d] = s;
}

__global__ __launch_bounds__(256, 2) void scan_s2(const ushort_t* __restrict__ dtfb,
    const ushort_t* __restrict__ ucb_in, const float* __restrict__ xdbl,
    const ushort_t* __restrict__ xzb, const float* __restrict__ A_log,
    const float* __restrict__ Dvec, const float* __restrict__ bnd_q,
    const float* __restrict__ bnd_s, ushort_t* __restrict__ ucb_out)
{
    __shared__ uint_t sdt[CHL * 256];
    __shared__ float sBC[CHL * 32];
    const int tid = threadIdx.x;
    const int bx = blockIdx.x;
    const int dg = bx & 7, c = (bx >> 3) & 31, b = bx >> 8;
    const int d = dg * 256 + tid;
    const int row0 = b * L_ + c * CHL;
    const float Dd = Dvec[d];

    float A_dn[16];
#pragma unroll
    for (int n = 0; n < 16; ++n) A_dn[n] = -__expf(A_log[(size_t)d * DS + n]);

    for (int k = 0; k < CHL; ++k) {
        size_t off = (size_t)(row0 + k) * DIN + d;
        sdt[k * 256 + tid] = (uint_t)dtfb[off] | ((uint_t)ucb_in[off] << 16);
    }
#pragma unroll
    for (int j = 0; j < 4; ++j) {
        int idx = tid + j * 256;
        int t = idx >> 5, jj = idx & 31;
        sBC[idx] = xdbl[(size_t)(row0 + t) * 96 + 64 + (jj & 1) * 16 + (jj >> 1)];
    }

    float h[16];
#pragma unroll
    for (int n = 0; n < 16; ++n) h[n] = 0.f;
    const size_t cb_base = (size_t)b * NCH * DIN + d;
    for (int cc = 0; cc < c; ++cc) {
        size_t idx = cb_base + (size_t)cc * DIN;
        float sv = bnd_s[idx];
        const float* qp = bnd_q + idx * 16;
        f32x4 qv[4];
#pragma unroll
        for (int j = 0; j < 4; ++j) qv[j] = *(const f32x4*)(qp + j * 4);
#pragma unroll
        for (int n = 0; n < 16; ++n)
            h[n] = fmaf(__expf(A_dn[n] * sv), h[n], qv[n >> 2][n & 3]);
    }
    __syncthreads();

    for (int k = 0; k < CHL; ++k) {
        uint_t pk = sdt[k * 256 + tid];
        float dtv = __uint_as_float(pk << 16);
        float uv  = __uint_as_float(pk & 0xffff0000u);
        float dtu = dtv * uv;
        float z = b2f(xzb[(size_t)(row0 + k) * (2 * DIN) + DIN + d]);
        float y = uv * Dd;
        f32x4 bcq[8];
#pragma unroll
        for (int j = 0; j < 8; ++j) bcq[j] = *(const f32x4*)(sBC + k * 32 + j * 4);
#pragma unroll
        for (int n = 0; n < 16; ++n) {
            float Bv = bcq[n >> 1][(n & 1) * 2];
            float Cv = bcq[n >> 1][(n & 1) * 2 + 1];
            h[n] = fmaf(__expf(dtv * A_dn[n]), h[n], dtu * Bv);
            y = fmaf(h[n], Cv, y);
        }
        y *= z * sigmoidf_(z);
        ucb_out[(size_t)(row0 + k) * DIN + d] = f2b(y);
    }
}

extern "C" void kernel_launch(void* const* d_in, const int* in_sizes, int n_in,
                              void* d_out, int out_size, void* d_ws, size_t ws_size,
                              hipStream_t stream)
{
    (void)in_sizes; (void)n_in; (void)out_size; (void)ws_size;
    const float* x      = (const float*)d_in[0];
    const float* W_in   = (const float*)d_in[1];
    const float* conv_w = (const float*)d_in[2];
    const float* conv_b = (const float*)d_in[3];
    const float* W_x    = (const float*)d_in[4];
    const float* W_dt   = (const float*)d_in[5];
    const float* b_dt   = (const float*)d_in[6];
    const float* A_log  = (const float*)d_in[7];
    const float* Dv     = (const float*)d_in[8];
    const float* W_out  = (const float*)d_in[9];
    float* out = (float*)d_out;

    // workspace layout
    float* xdbl    = (float*)d_ws;                       //   196,608 f32
    float* pws     = xdbl + 196608;                      // 1,572,864 f32
    float* bnd_q   = pws + 1572864;                      // 2,097,152 f32
    float* bnd_s   = bnd_q + 2097152;                    //   131,072 f32
    ushort_t* dtfb = (ushort_t*)(bnd_s + 131072);        // 4,194,304 u16
    ushort_t* xzb  = dtfb + 4194304;                     // 8,388,608
    ushort_t* ucb  = xzb + 8388608;                      // 4,194,304
    ushort_t* xb   = ucb + 4194304;                      // 2,097,152 (x/h bf16)
    ushort_t* wib  = xb + 2097152;                       // 8,388,608
    ushort_t* wxb  = wib + 8388608;                      //   393,216
    ushort_t* wdb  = wxb + 393216;                       //   262,144
    ushort_t* wob  = wdb + 262144;                       // 4,194,304

    const int M = B_ * L_;
    const int NT = 2097152 + 8388608 + 393216 + 262144 + 4194304;
    f2b_all_k<<<(NT / 4) / 256, 256, 0, stream>>>(
        x, xb, 2097152, W_in, wib, 8388608, W_x, wxb, 393216,
        W_dt, wdb, 262144, W_out, wob, 4194304);

    for (int layer = 0; layer < 2; ++layer) {
        // xzb = bf16( h @ W_in^T )  [M, 4096]
        mgemm_in<<<dim3(4096 / 128, M / 128), 256, 0, stream>>>(
            xb, wib + (size_t)layer * 4194304, xzb, M, 2 * DIN, DM, DM, DM);
        // ucb = bf16(silu(conv(u) + b))
        conv8_k<<<(B_ * L_ * DIN / 8) / 256, 256, 0, stream>>>(
            xzb, conv_w + (size_t)layer * DIN * 4, conv_b + (size_t)layer * DIN, ucb);
        // pws[z] = partial (u @ W_x^T) over K-slices  [M, 96] x8
        mgemm_sk<<<dim3(1, M / 128, 8), 256, 0, stream>>>(
            ucb, wxb + (size_t)layer * 196608, pws, M, 96, DIN / 8, DIN, DIN);
        // fused: reduce partials + dt-proj softplus -> dtfb; bx==0 writes xdbl[:,64:96]
        mgemm_dtf<<<dim3(16, 16), 256, 0, stream>>>(
            pws, wdb + (size_t)layer * 131072, b_dt + (size_t)layer * DIN, xdbl, dtfb);
        // chunk-parallel scan
        const float* Al = A_log + (size_t)layer * DIN * DS;
        scan_s1<<<B_ * NCH * 8, 256, 0, stream>>>(dtfb, ucb, xdbl, Al, bnd_q, bnd_s);
        scan_s2<<<B_ * NCH * 8, 256, 0, stream>>>(dtfb, ucb, xdbl, xzb, Al,
            Dv + (size_t)layer * DIN, bnd_q, bnd_s, ucb);
        // out-proj: layer0 -> xb (bf16 h); layer1 -> out = acc + x
        if (layer == 0)
            mgemm_n64<3><<<dim3(1024 / 64, M / 128), 256, 0, stream>>>(
                ucb, wob + (size_t)layer * 2097152, nullptr, xb, nullptr,
                M, DM, DIN, DIN, DIN);
        else
            mgemm_n64<4><<<dim3(1024 / 64, M / 128), 256, 0, stream>>>(
                ucb, wob + (size_t)layer * 2097152, out, nullptr, x,
                M, DM, DIN, DIN, DIN);
    }
}

// Round 11
// 436.451 us; speedup vs baseline: 1.0466x; 1.0335x over previous
//
#include <hip/hip_runtime.h>
#include <hip/hip_bf16.h>
#include <math.h>

#define B_ 2
#define L_ 1024
#define DM 1024
#define DIN 2048
#define DS 16
#define DTR 64
#define CHL 32      // chunk length
#define NCH 32      // chunks per sequence

typedef __attribute__((ext_vector_type(8))) short bf16x8;
typedef __attribute__((ext_vector_type(8))) unsigned short u16x8;
typedef __attribute__((ext_vector_type(4))) unsigned short u16x4;
typedef __attribute__((ext_vector_type(4))) float f32x4;
typedef unsigned short ushort_t;
typedef unsigned int uint_t;

__device__ __forceinline__ float sigmoidf_(float x) { return 1.f / (1.f + __expf(-x)); }
__device__ __forceinline__ ushort_t f2b(float f) {
    uint_t b = __float_as_uint(f);
    return (ushort_t)((b + 0x7FFFu + ((b >> 16) & 1u)) >> 16);
}
__device__ __forceinline__ float b2f(ushort_t u) {
    return __uint_as_float(((uint_t)u) << 16);
}

// fused f32 -> bf16 (RTN), 4 elems/thread
__global__ __launch_bounds__(256) void f2b_all_k(
    const float* __restrict__ s0, ushort_t* __restrict__ d0, int n0,
    const float* __restrict__ s1, ushort_t* __restrict__ d1, int n1,
    const float* __restrict__ s2, ushort_t* __restrict__ d2, int n2,
    const float* __restrict__ s3, ushort_t* __restrict__ d3, int n3,
    const float* __restrict__ s4, ushort_t* __restrict__ d4, int n4)
{
    int i = (blockIdx.x * 256 + threadIdx.x) * 4;
    const float* s; ushort_t* d;
    if (i < n0) { s = s0; d = d0; }
    else { i -= n0;
    if (i < n1) { s = s1; d = d1; }
    else { i -= n1;
    if (i < n2) { s = s2; d = d2; }
    else { i -= n2;
    if (i < n3) { s = s3; d = d3; }
    else { i -= n3;
    if (i < n4) { s = s4; d = d4; }
    else return; }}}}
    float4 v = *(const float4*)(s + i);
    u16x4 o;
    o[0] = f2b(v.x); o[1] = f2b(v.y); o[2] = f2b(v.z); o[3] = f2b(v.w);
    *(u16x4*)(d + i) = o;
}

// XCD-aware bijective swizzle of linear wg id (nwg % 8 == 0)
__device__ __forceinline__ int xcd_swz(int wgid, int nwg) {
    int cpx = nwg >> 3;
    return (wgid & 7) * cpx + (wgid >> 3);
}

// ---------------- MFMA GEMM 128x128, dbuf (in-proj), bf16 out ------------------
__global__ __launch_bounds__(256) void mgemm_in(const ushort_t* __restrict__ A,
    const ushort_t* __restrict__ Bt, ushort_t* __restrict__ Cb,
    int M, int N, int K, int lda, int ldb)
{
    __shared__ ushort_t sA[2][128 * 32];
    __shared__ ushort_t sB[2][128 * 32];
    const int tid = threadIdx.x;
    const int lane = tid & 63, wv = tid >> 6;
    const int wm = wv >> 1, wn = wv & 1;
    const int swz = xcd_swz(blockIdx.y * gridDim.x + blockIdx.x, gridDim.x * gridDim.y);
    const int m0 = (swz / gridDim.x) * 128, n0 = (swz % gridDim.x) * 128;
    const int sr = tid >> 2;
    const int sc = (tid & 3) * 8;
    f32x4 acc[4][4] = {};

#pragma unroll
    for (int j = 0; j < 2; ++j) {
        int ra = sr + j * 64;
        __builtin_amdgcn_global_load_lds(
            (const uint_t*)(A + (size_t)(m0 + ra) * lda + sc),
            (uint_t*)(sA[0] + ra * 32 + sc), 16, 0, 0);
        __builtin_amdgcn_global_load_lds(
            (const uint_t*)(Bt + (size_t)(n0 + ra) * ldb + sc),
            (uint_t*)(sB[0] + ra * 32 + sc), 16, 0, 0);
    }
    __syncthreads();
    int cur = 0;
    for (int k0 = 0; k0 < K; k0 += 32) {
        if (k0 + 32 < K) {
            int nxt = cur ^ 1;
#pragma unroll
            for (int j = 0; j < 2; ++j) {
                int ra = sr + j * 64;
                __builtin_amdgcn_global_load_lds(
                    (const uint_t*)(A + (size_t)(m0 + ra) * lda + k0 + 32 + sc),
                    (uint_t*)(sA[nxt] + ra * 32 + sc), 16, 0, 0);
                __builtin_amdgcn_global_load_lds(
                    (const uint_t*)(Bt + (size_t)(n0 + ra) * ldb + k0 + 32 + sc),
                    (uint_t*)(sB[nxt] + ra * 32 + sc), 16, 0, 0);
            }
        }
        bf16x8 af[4], bfr[4];
#pragma unroll
        for (int i = 0; i < 4; ++i) {
            af[i]  = *(const bf16x8*)(sA[cur] + (wm * 64 + i * 16 + (lane & 15)) * 32 + (lane >> 4) * 8);
            bfr[i] = *(const bf16x8*)(sB[cur] + (wn * 64 + i * 16 + (lane & 15)) * 32 + (lane >> 4) * 8);
        }
#pragma unroll
        for (int i = 0; i < 4; ++i)
#pragma unroll
            for (int jj = 0; jj < 4; ++jj)
                acc[i][jj] = __builtin_amdgcn_mfma_f32_16x16x32_bf16(af[i], bfr[jj], acc[i][jj], 0, 0, 0);
        __syncthreads();
        cur ^= 1;
    }

    const int cr = (lane >> 4) * 4, cc = lane & 15;
#pragma unroll
    for (int i = 0; i < 4; ++i) {
        int mrow = m0 + wm * 64 + i * 16 + cr;
#pragma unroll
        for (int jj = 0; jj < 4; ++jj) {
            int ncol = n0 + wn * 64 + jj * 16 + cc;
#pragma unroll
            for (int r = 0; r < 4; ++r)
                Cb[(size_t)(mrow + r) * N + ncol] = f2b(acc[i][jj][r]);
        }
    }
}

// ---------------- MFMA GEMM 128xK split-K (N=96 W_x proj), dbuf ----------------
__global__ __launch_bounds__(256) void mgemm_sk(const ushort_t* __restrict__ A,
    const ushort_t* __restrict__ Bt, float* __restrict__ P,
    int M, int N, int Kslice, int lda, int ldb)
{
    __shared__ ushort_t sA[2][128 * 32];
    __shared__ ushort_t sB[2][128 * 32];
    const int tid = threadIdx.x;
    const int lane = tid & 63, wv = tid >> 6;
    const int wm = wv >> 1, wn = wv & 1;
    const int m0 = blockIdx.y * 128;
    const int kbase = blockIdx.z * Kslice;
    const int sr = tid >> 2;
    const int sc = (tid & 3) * 8;
    f32x4 acc[4][4] = {};

#pragma unroll
    for (int j = 0; j < 2; ++j) {
        int ra = sr + j * 64;
        __builtin_amdgcn_global_load_lds(
            (const uint_t*)(A + (size_t)(m0 + ra) * lda + kbase + sc),
            (uint_t*)(sA[0] + ra * 32 + sc), 16, 0, 0);
        int gb = ra; if (gb >= N) gb = N - 1;
        __builtin_amdgcn_global_load_lds(
            (const uint_t*)(Bt + (size_t)gb * ldb + kbase + sc),
            (uint_t*)(sB[0] + ra * 32 + sc), 16, 0, 0);
    }
    __syncthreads();
    int cur = 0;
    for (int k0 = kbase; k0 < kbase + Kslice; k0 += 32) {
        if (k0 + 32 < kbase + Kslice) {
            int nxt = cur ^ 1;
#pragma unroll
            for (int j = 0; j < 2; ++j) {
                int ra = sr + j * 64;
                __builtin_amdgcn_global_load_lds(
                    (const uint_t*)(A + (size_t)(m0 + ra) * lda + k0 + 32 + sc),
                    (uint_t*)(sA[nxt] + ra * 32 + sc), 16, 0, 0);
                int gb = ra; if (gb >= N) gb = N - 1;
                __builtin_amdgcn_global_load_lds(
                    (const uint_t*)(Bt + (size_t)gb * ldb + k0 + 32 + sc),
                    (uint_t*)(sB[nxt] + ra * 32 + sc), 16, 0, 0);
            }
        }
        bf16x8 af[4], bfr[4];
#pragma unroll
        for (int i = 0; i < 4; ++i) {
            af[i]  = *(const bf16x8*)(sA[cur] + (wm * 64 + i * 16 + (lane & 15)) * 32 + (lane >> 4) * 8);
            bfr[i] = *(const bf16x8*)(sB[cur] + (wn * 64 + i * 16 + (lane & 15)) * 32 + (lane >> 4) * 8);
        }
#pragma unroll
        for (int i = 0; i < 4; ++i)
#pragma unroll
            for (int jj = 0; jj < 4; ++jj)
                acc[i][jj] = __builtin_amdgcn_mfma_f32_16x16x32_bf16(af[i], bfr[jj], acc[i][jj], 0, 0, 0);
        __syncthreads();
        cur ^= 1;
    }

    const int cr = (lane >> 4) * 4, cc = lane & 15;
    float* Pz = P + (size_t)blockIdx.z * M * 96;
#pragma unroll
    for (int i = 0; i < 4; ++i) {
        int mrow = m0 + wm * 64 + i * 16 + cr;
#pragma unroll
        for (int jj = 0; jj < 4; ++jj) {
            int ncol = wn * 64 + jj * 16 + cc;
            if (ncol < 96) {
#pragma unroll
                for (int r = 0; r < 4; ++r)
                    Pz[(size_t)(mrow + r) * 96 + ncol] = acc[i][jj][r];
            }
        }
    }
}

// ---- fused: reduce split-K partials (cols 0:64 -> LDS bf16 A) + dt-proj GEMM --
__global__ __launch_bounds__(256) void mgemm_dtf(const float* __restrict__ P,
    const ushort_t* __restrict__ Wd, const float* __restrict__ bias,
    float* __restrict__ xdbl, ushort_t* __restrict__ dtfb)
{
    __shared__ ushort_t sA[2][128 * 36];   // pad 36/row-half: <=2-way banks
    __shared__ ushort_t sB[2][128 * 32];
    const int tid = threadIdx.x;
    const int lane = tid & 63, wv = tid >> 6;
    const int wm = wv >> 1, wn = wv & 1;
    const int n0 = blockIdx.x * 128, m0 = blockIdx.y * 128;

#pragma unroll
    for (int kh = 0; kh < 2; ++kh)
#pragma unroll
        for (int it = 0; it < 2; ++it) {
            int ci = tid + it * 256;             // 0..511
            int row = ci >> 2, cc = ci & 3;
            __builtin_amdgcn_global_load_lds(
                (const uint_t*)(Wd + (size_t)(n0 + row) * 64 + kh * 32 + cc * 8),
                (uint_t*)(sB[kh] + (size_t)ci * 8), 16, 0, 0);
        }

#pragma unroll
    for (int it = 0; it < 8; ++it) {
        int ci = tid + it * 256;                 // 0..2047
        int row = ci >> 4, c4 = (ci & 15) * 4;
        float s0 = 0.f, s1 = 0.f, s2 = 0.f, s3 = 0.f;
#pragma unroll
        for (int z = 0; z < 8; ++z) {
            f32x4 v = *(const f32x4*)(P + (size_t)z * 196608 + (size_t)(m0 + row) * 96 + c4);
            s0 += v[0]; s1 += v[1]; s2 += v[2]; s3 += v[3];
        }
        u16x4 o; o[0] = f2b(s0); o[1] = f2b(s1); o[2] = f2b(s2); o[3] = f2b(s3);
        int kh = c4 >> 5, cl = c4 & 31;
        *(u16x4*)(sA[kh] + row * 36 + cl) = o;
    }
    if (blockIdx.x == 0) {
#pragma unroll
        for (int it = 0; it < 4; ++it) {
            int ci = tid + it * 256;             // 0..1023
            int row = ci >> 3, c4 = (ci & 7) * 4;
            f32x4 s = {0.f, 0.f, 0.f, 0.f};
#pragma unroll
            for (int z = 0; z < 8; ++z) {
                f32x4 v = *(const f32x4*)(P + (size_t)z * 196608 + (size_t)(m0 + row) * 96 + 64 + c4);
                s[0] += v[0]; s[1] += v[1]; s[2] += v[2]; s[3] += v[3];
            }
            *(f32x4*)(xdbl + (size_t)(m0 + row) * 96 + 64 + c4) = s;
        }
    }
    __syncthreads();

    f32x4 acc[4][4] = {};
#pragma unroll
    for (int ks = 0; ks < 2; ++ks) {
        bf16x8 af[4], bfr[4];
#pragma unroll
        for (int i = 0; i < 4; ++i) {
            af[i]  = *(const bf16x8*)(sA[ks] + (wm * 64 + i * 16 + (lane & 15)) * 36 + (lane >> 4) * 8);
            bfr[i] = *(const bf16x8*)(sB[ks] + (wn * 64 + i * 16 + (lane & 15)) * 32 + (lane >> 4) * 8);
        }
#pragma unroll
        for (int i = 0; i < 4; ++i)
#pragma unroll
            for (int jj = 0; jj < 4; ++jj)
                acc[i][jj] = __builtin_amdgcn_mfma_f32_16x16x32_bf16(af[i], bfr[jj], acc[i][jj], 0, 0, 0);
    }

    const int cr = (lane >> 4) * 4, cc = lane & 15;
#pragma unroll
    for (int i = 0; i < 4; ++i) {
        int mrow = m0 + wm * 64 + i * 16 + cr;
#pragma unroll
        for (int jj = 0; jj < 4; ++jj) {
            int ncol = n0 + wn * 64 + jj * 16 + cc;
#pragma unroll
            for (int r = 0; r < 4; ++r) {
                float s = acc[i][jj][r] + bias[ncol];
                dtfb[(size_t)(mrow + r) * DIN + ncol] =
                    f2b((s > 20.f) ? s : log1pf(expf(s)));
            }
        }
    }
}

// ---------------- MFMA GEMM 128x64 split-K x2 (out-proj), f32 partial ----------
__global__ __launch_bounds__(256) void mgemm_o(const ushort_t* __restrict__ A,
    const ushort_t* __restrict__ Bt, float* __restrict__ P,
    int M, int N, int Kslice, int lda, int ldb)
{
    __shared__ ushort_t sA[2][128 * 32];
    __shared__ ushort_t sB[2][64 * 32];
    const int tid = threadIdx.x;
    const int lane = tid & 63, wv = tid >> 6;
    const int m0 = blockIdx.y * 128, n0 = blockIdx.x * 64;
    const int kbase = blockIdx.z * Kslice;
    const int sr = tid >> 2;
    const int sc = (tid & 3) * 8;
    f32x4 acc[2][4] = {};

#pragma unroll
    for (int j = 0; j < 2; ++j) {
        int ra = sr + j * 64;
        __builtin_amdgcn_global_load_lds(
            (const uint_t*)(A + (size_t)(m0 + ra) * lda + kbase + sc),
            (uint_t*)(sA[0] + ra * 32 + sc), 16, 0, 0);
    }
    __builtin_amdgcn_global_load_lds(
        (const uint_t*)(Bt + (size_t)(n0 + sr) * ldb + kbase + sc),
        (uint_t*)(sB[0] + sr * 32 + sc), 16, 0, 0);
    __syncthreads();
    int cur = 0;
    for (int k0 = kbase; k0 < kbase + Kslice; k0 += 32) {
        if (k0 + 32 < kbase + Kslice) {
            int nxt = cur ^ 1;
#pragma unroll
            for (int j = 0; j < 2; ++j) {
                int ra = sr + j * 64;
                __builtin_amdgcn_global_load_lds(
                    (const uint_t*)(A + (size_t)(m0 + ra) * lda + k0 + 32 + sc),
                    (uint_t*)(sA[nxt] + ra * 32 + sc), 16, 0, 0);
            }
            __builtin_amdgcn_global_load_lds(
                (const uint_t*)(Bt + (size_t)(n0 + sr) * ldb + k0 + 32 + sc),
                (uint_t*)(sB[nxt] + sr * 32 + sc), 16, 0, 0);
        }
        bf16x8 af[2], bfr[4];
#pragma unroll
        for (int i = 0; i < 2; ++i)
            af[i]  = *(const bf16x8*)(sA[cur] + (wv * 32 + i * 16 + (lane & 15)) * 32 + (lane >> 4) * 8);
#pragma unroll
        for (int jj = 0; jj < 4; ++jj)
            bfr[jj] = *(const bf16x8*)(sB[cur] + (jj * 16 + (lane & 15)) * 32 + (lane >> 4) * 8);
#pragma unroll
        for (int i = 0; i < 2; ++i)
#pragma unroll
            for (int jj = 0; jj < 4; ++jj)
                acc[i][jj] = __builtin_amdgcn_mfma_f32_16x16x32_bf16(af[i], bfr[jj], acc[i][jj], 0, 0, 0);
        __syncthreads();
        cur ^= 1;
    }

    const int cr = (lane >> 4) * 4, cc = lane & 15;
    float* Pz = P + (size_t)blockIdx.z * M * DM;
#pragma unroll
    for (int i = 0; i < 2; ++i) {
        int mrow = m0 + wv * 32 + i * 16 + cr;
#pragma unroll
        for (int jj = 0; jj < 4; ++jj) {
            int ncol = n0 + jj * 16 + cc;
#pragma unroll
            for (int r = 0; r < 4; ++r)
                Pz[(size_t)(mrow + r) * DM + ncol] = acc[i][jj][r];
        }
    }
}

// out-proj reduce: EPI 3 -> bf16 h; EPI 4 -> out = P0+P1+res
template<int EPI>
__global__ __launch_bounds__(256) void ored_k(const float* __restrict__ P,
    const float* __restrict__ res, float* __restrict__ Cf, ushort_t* __restrict__ Cb)
{
    int i = (blockIdx.x * 256 + threadIdx.x) * 4;
    f32x4 a = *(const f32x4*)(P + i);
    f32x4 b = *(const f32x4*)(P + 2097152 + i);
    if (EPI == 3) {
        u16x4 o;
#pragma unroll
        for (int e = 0; e < 4; ++e) o[e] = f2b(a[e] + b[e]);
        *(u16x4*)(Cb + i) = o;
    } else {
        f32x4 r = *(const f32x4*)(res + i);
        f32x4 o;
#pragma unroll
        for (int e = 0; e < 4; ++e) o[e] = a[e] + b[e] + r[e];
        *(f32x4*)(Cf + i) = o;
    }
}

// conv + silu, 8 channels per thread
__global__ __launch_bounds__(256) void conv8_k(const ushort_t* __restrict__ xzb,
    const float* __restrict__ cw, const float* __restrict__ cb,
    ushort_t* __restrict__ ucb)
{
    int idx8 = blockIdx.x * 256 + threadIdx.x;
    int d8 = (idx8 & 255) * 8;
    int t = (idx8 >> 8) & (L_ - 1);
    int b = idx8 >> 18;
    const ushort_t* base = xzb + (size_t)b * L_ * (2 * DIN) + d8;
    float acc[8];
    const float4* cb4 = (const float4*)(cb + d8);
    float4 cbl = cb4[0], cbh = cb4[1];
#pragma unroll
    for (int e = 0; e < 4; ++e) { acc[e] = ((const float*)&cbl)[e]; acc[4 + e] = ((const float*)&cbh)[e]; }
    float4 cwv[8];
#pragma unroll
    for (int e = 0; e < 8; ++e) cwv[e] = ((const float4*)cw)[d8 + e];
#pragma unroll
    for (int j = 0; j < 4; ++j) {
        int tt = t - 3 + j;
        if (tt >= 0) {
            u16x8 row = *(const u16x8*)(base + (size_t)tt * (2 * DIN));
#pragma unroll
            for (int e = 0; e < 8; ++e)
                acc[e] = fmaf(((const float*)&cwv[e])[j], b2f(row[e]), acc[e]);
        }
    }
    u16x8 ob;
#pragma unroll
    for (int e = 0; e < 8; ++e) {
        float v = acc[e] * sigmoidf_(acc[e]);
        ob[e] = f2b(v);
    }
    *(u16x8*)(ucb + (size_t)idx8 * 8) = ob;
}

// ---------------- chunk-parallel scan, 16 states per THREAD -------------------
// S1: vectorized LDS staging via global_load_lds (16B/lane)
__global__ __launch_bounds__(256, 2) void scan_s1(const ushort_t* __restrict__ dtfb,
    const ushort_t* __restrict__ ucb, const float* __restrict__ xdbl,
    const float* __restrict__ A_log,
    float* __restrict__ bnd_q, float* __restrict__ bnd_s)
{
    __shared__ ushort_t s_dt[CHL * 256];
    __shared__ ushort_t s_u[CHL * 256];
    __shared__ float sB[CHL * 16];
    const int tid = threadIdx.x;
    const int bx = blockIdx.x;
    const int dg = bx & 7, c = (bx >> 3) & 31, b = bx >> 8;
    const int d = dg * 256 + tid;
    const int dbase = dg * 256;
    const int row0 = b * L_ + c * CHL;

    float A_dn[16];
#pragma unroll
    for (int n = 0; n < 16; ++n) A_dn[n] = -__expf(A_log[(size_t)d * DS + n]);

    const int rr = tid >> 5, c16 = (tid & 31) * 8;
#pragma unroll
    for (int it = 0; it < 4; ++it) {
        int k = rr + it * 8;
        size_t gro = (size_t)(row0 + k) * DIN + dbase + c16;
        __builtin_amdgcn_global_load_lds((const uint_t*)(dtfb + gro),
            (uint_t*)(s_dt + k * 256 + c16), 16, 0, 0);
        __builtin_amdgcn_global_load_lds((const uint_t*)(ucb + gro),
            (uint_t*)(s_u + k * 256 + c16), 16, 0, 0);
    }
#pragma unroll
    for (int j = 0; j < 2; ++j) {
        int idx = tid + j * 256;
        int t = idx >> 4, n = idx & 15;
        sB[idx] = xdbl[(size_t)(row0 + t) * 96 + 64 + n];
    }
    __syncthreads();

    float q[16];
#pragma unroll
    for (int n = 0; n < 16; ++n) q[n] = 0.f;
    float s = 0.f;
    for (int k = 0; k < CHL; ++k) {
        float dtv = b2f(s_dt[k * 256 + tid]);
        float uv  = b2f(s_u[k * 256 + tid]);
        float dtu = dtv * uv;
        s += dtv;
        f32x4 Bq[4];
#pragma unroll
        for (int j = 0; j < 4; ++j) Bq[j] = *(const f32x4*)(sB + k * 16 + j * 4);
#pragma unroll
        for (int n = 0; n < 16; ++n)
            q[n] = fmaf(__expf(dtv * A_dn[n]), q[n], dtu * Bq[n >> 2][n & 3]);
    }
    float* qp = bnd_q + ((size_t)(b * NCH + c) * DIN + d) * 16;
#pragma unroll
    for (int j = 0; j < 4; ++j)
        *(f32x4*)(qp + j * 4) = (f32x4){q[j * 4], q[j * 4 + 1], q[j * 4 + 2], q[j * 4 + 3]};
    bnd_s[(size_t)(b * NCH + c) * DIN + d] = s;
}

// S2: vectorized staging (dt/u/z), y written back into s_dt, vectorized store
__global__ __launch_bounds__(256, 2) void scan_s2(const ushort_t* __restrict__ dtfb,
    const ushort_t* __restrict__ ucb_in, const float* __restrict__ xdbl,
    const ushort_t* __restrict__ xzb, const float* __restrict__ A_log,
    const float* __restrict__ Dvec, const float* __restrict__ bnd_q,
    const float* __restrict__ bnd_s, ushort_t* __restrict__ ucb_out)
{
    __shared__ ushort_t s_dt[CHL * 256];   // reused for y output
    __shared__ ushort_t s_u[CHL * 256];
    __shared__ ushort_t s_z[CHL * 256];
    __shared__ float sBC[CHL * 32];
    const int tid = threadIdx.x;
    const int bx = blockIdx.x;
    const int dg = bx & 7, c = (bx >> 3) & 31, b = bx >> 8;
    const int d = dg * 256 + tid;
    const int dbase = dg * 256;
    const int row0 = b * L_ + c * CHL;
    const float Dd = Dvec[d];

    float A_dn[16];
#pragma unroll
    for (int n = 0; n < 16; ++n) A_dn[n] = -__expf(A_log[(size_t)d * DS + n]);

    const int rr = tid >> 5, c16 = (tid & 31) * 8;
#pragma unroll
    for (int it = 0; it < 4; ++it) {
        int k = rr + it * 8;
        size_t gro = (size_t)(row0 + k) * DIN + dbase + c16;
        __builtin_amdgcn_global_load_lds((const uint_t*)(dtfb + gro),
            (uint_t*)(s_dt + k * 256 + c16), 16, 0, 0);
        __builtin_amdgcn_global_load_lds((const uint_t*)(ucb_in + gro),
            (uint_t*)(s_u + k * 256 + c16), 16, 0, 0);
        __builtin_amdgcn_global_load_lds(
            (const uint_t*)(xzb + (size_t)(row0 + k) * (2 * DIN) + DIN + dbase + c16),
            (uint_t*)(s_z + k * 256 + c16), 16, 0, 0);
    }
#pragma unroll
    for (int j = 0; j < 4; ++j) {
        int idx = tid + j * 256;
        int t = idx >> 5, jj = idx & 31;
        sBC[idx] = xdbl[(size_t)(row0 + t) * 96 + 64 + (jj & 1) * 16 + (jj >> 1)];
    }

    // inline boundary combine: H before chunk c (global reads, overlap staging)
    float h[16];
#pragma unroll
    for (int n = 0; n < 16; ++n) h[n] = 0.f;
    const size_t cb_base = (size_t)b * NCH * DIN + d;
    for (int cc = 0; cc < c; ++cc) {
        size_t idx = cb_base + (size_t)cc * DIN;
        float sv = bnd_s[idx];
        const float* qp = bnd_q + idx * 16;
        f32x4 qv[4];
#pragma unroll
        for (int j = 0; j < 4; ++j) qv[j] = *(const f32x4*)(qp + j * 4);
#pragma unroll
        for (int n = 0; n < 16; ++n)
            h[n] = fmaf(__expf(A_dn[n] * sv), h[n], qv[n >> 2][n & 3]);
    }
    __syncthreads();

    for (int k = 0; k < CHL; ++k) {
        float dtv = b2f(s_dt[k * 256 + tid]);
        float uv  = b2f(s_u[k * 256 + tid]);
        float z   = b2f(s_z[k * 256 + tid]);
        float dtu = dtv * uv;
        float y = uv * Dd;
        f32x4 bcq[8];
#pragma unroll
        for (int j = 0; j < 8; ++j) bcq[j] = *(const f32x4*)(sBC + k * 32 + j * 4);
#pragma unroll
        for (int n = 0; n < 16; ++n) {
            float Bv = bcq[n >> 1][(n & 1) * 2];
            float Cv = bcq[n >> 1][(n & 1) * 2 + 1];
            h[n] = fmaf(__expf(dtv * A_dn[n]), h[n], dtu * Bv);
            y = fmaf(h[n], Cv, y);
        }
        y *= z * sigmoidf_(z);
        s_dt[k * 256 + tid] = f2b(y);    // own slot, already consumed this step
    }
    __syncthreads();
    // vectorized store (u16x8 per thread per row-group)
#pragma unroll
    for (int it = 0; it < 4; ++it) {
        int k = rr + it * 8;
        *(u16x8*)(ucb_out + (size_t)(row0 + k) * DIN + dbase + c16) =
            *(const u16x8*)(s_dt + k * 256 + c16);
    }
}

extern "C" void kernel_launch(void* const* d_in, const int* in_sizes, int n_in,
                              void* d_out, int out_size, void* d_ws, size_t ws_size,
                              hipStream_t stream)
{
    (void)in_sizes; (void)n_in; (void)out_size; (void)ws_size;
    const float* x      = (const float*)d_in[0];
    const float* W_in   = (const float*)d_in[1];
    const float* conv_w = (const float*)d_in[2];
    const float* conv_b = (const float*)d_in[3];
    const float* W_x    = (const float*)d_in[4];
    const float* W_dt   = (const float*)d_in[5];
    const float* b_dt   = (const float*)d_in[6];
    const float* A_log  = (const float*)d_in[7];
    const float* Dv     = (const float*)d_in[8];
    const float* W_out  = (const float*)d_in[9];
    float* out = (float*)d_out;

    // workspace layout
    float* xdbl    = (float*)d_ws;                       //   196,608 f32
    float* pws     = xdbl + 196608;                      // 1,572,864 f32
    float* bnd_q   = pws + 1572864;                      // 2,097,152 f32
    float* bnd_s   = bnd_q + 2097152;                    //   131,072 f32
    ushort_t* dtfb = (ushort_t*)(bnd_s + 131072);        // 4,194,304 u16
    ushort_t* xzb  = dtfb + 4194304;                     // 8,388,608
    ushort_t* ucb  = xzb + 8388608;                      // 4,194,304
    ushort_t* xb   = ucb + 4194304;                      // 2,097,152 (x/h bf16)
    ushort_t* wib  = xb + 2097152;                       // 8,388,608
    ushort_t* wxb  = wib + 8388608;                      //   393,216
    ushort_t* wdb  = wxb + 393216;                       //   262,144
    ushort_t* wob  = wdb + 262144;                       // 4,194,304
    float* pwo     = (float*)(wob + 4194304);            // 4,194,304 f32 (out-proj partials)

    const int M = B_ * L_;
    const int NT = 2097152 + 8388608 + 393216 + 262144 + 4194304;
    f2b_all_k<<<(NT / 4) / 256, 256, 0, stream>>>(
        x, xb, 2097152, W_in, wib, 8388608, W_x, wxb, 393216,
        W_dt, wdb, 262144, W_out, wob, 4194304);

    for (int layer = 0; layer < 2; ++layer) {
        // xzb = bf16( h @ W_in^T )  [M, 4096]
        mgemm_in<<<dim3(4096 / 128, M / 128), 256, 0, stream>>>(
            xb, wib + (size_t)layer * 4194304, xzb, M, 2 * DIN, DM, DM, DM);
        // ucb = bf16(silu(conv(u) + b))
        conv8_k<<<(B_ * L_ * DIN / 8) / 256, 256, 0, stream>>>(
            xzb, conv_w + (size_t)layer * DIN * 4, conv_b + (size_t)layer * DIN, ucb);
        // pws[z] = partial (u @ W_x^T) over K-slices  [M, 96] x8
        mgemm_sk<<<dim3(1, M / 128, 8), 256, 0, stream>>>(
            ucb, wxb + (size_t)layer * 196608, pws, M, 96, DIN / 8, DIN, DIN);
        // fused: reduce partials + dt-proj softplus -> dtfb; bx==0 writes xdbl[:,64:96]
        mgemm_dtf<<<dim3(16, 16), 256, 0, stream>>>(
            pws, wdb + (size_t)layer * 131072, b_dt + (size_t)layer * DIN, xdbl, dtfb);
        // chunk-parallel scan
        const float* Al = A_log + (size_t)layer * DIN * DS;
        scan_s1<<<B_ * NCH * 8, 256, 0, stream>>>(dtfb, ucb, xdbl, Al, bnd_q, bnd_s);
        scan_s2<<<B_ * NCH * 8, 256, 0, stream>>>(dtfb, ucb, xdbl, xzb, Al,
            Dv + (size_t)layer * DIN, bnd_q, bnd_s, ucb);
        // out-proj split-K x2 -> partials, then fused reduce
        mgemm_o<<<dim3(1024 / 64, M / 128, 2), 256, 0, stream>>>(
            ucb, wob + (size_t)layer * 2097152, pwo, M, DM, DIN / 2, DIN, DIN);
        if (layer == 0)
            ored_k<3><<<(2097152 / 4) / 256, 256, 0, stream>>>(pwo, nullptr, nullptr, xb);
        else
            ored_k<4><<<(2097152 / 4) / 256, 256, 0, stream>>>(pwo, x, out, nullptr);
    }
}

// Round 12
// 425.594 us; speedup vs baseline: 1.0733x; 1.0255x over previous
//
#include <hip/hip_runtime.h>
#include <hip/hip_bf16.h>
#include <math.h>

#define B_ 2
#define L_ 1024
#define DM 1024
#define DIN 2048
#define DS 16
#define DTR 64
#define CHL 16      // chunk length
#define NCH 64      // chunks per sequence

typedef __attribute__((ext_vector_type(8))) short bf16x8;
typedef __attribute__((ext_vector_type(8))) unsigned short u16x8;
typedef __attribute__((ext_vector_type(4))) unsigned short u16x4;
typedef __attribute__((ext_vector_type(4))) float f32x4;
typedef unsigned short ushort_t;
typedef unsigned int uint_t;

__device__ __forceinline__ float sigmoidf_(float x) { return 1.f / (1.f + __expf(-x)); }
__device__ __forceinline__ ushort_t f2b(float f) {
    uint_t b = __float_as_uint(f);
    return (ushort_t)((b + 0x7FFFu + ((b >> 16) & 1u)) >> 16);
}
__device__ __forceinline__ float b2f(ushort_t u) {
    return __uint_as_float(((uint_t)u) << 16);
}

// fused f32 -> bf16 (RTN), 4 elems/thread
__global__ __launch_bounds__(256) void f2b_all_k(
    const float* __restrict__ s0, ushort_t* __restrict__ d0, int n0,
    const float* __restrict__ s1, ushort_t* __restrict__ d1, int n1,
    const float* __restrict__ s2, ushort_t* __restrict__ d2, int n2,
    const float* __restrict__ s3, ushort_t* __restrict__ d3, int n3,
    const float* __restrict__ s4, ushort_t* __restrict__ d4, int n4)
{
    int i = (blockIdx.x * 256 + threadIdx.x) * 4;
    const float* s; ushort_t* d;
    if (i < n0) { s = s0; d = d0; }
    else { i -= n0;
    if (i < n1) { s = s1; d = d1; }
    else { i -= n1;
    if (i < n2) { s = s2; d = d2; }
    else { i -= n2;
    if (i < n3) { s = s3; d = d3; }
    else { i -= n3;
    if (i < n4) { s = s4; d = d4; }
    else return; }}}}
    float4 v = *(const float4*)(s + i);
    u16x4 o;
    o[0] = f2b(v.x); o[1] = f2b(v.y); o[2] = f2b(v.z); o[3] = f2b(v.w);
    *(u16x4*)(d + i) = o;
}

// XCD-aware bijective swizzle of linear wg id (nwg % 8 == 0)
__device__ __forceinline__ int xcd_swz(int wgid, int nwg) {
    int cpx = nwg >> 3;
    return (wgid & 7) * cpx + (wgid >> 3);
}

// ---------------- MFMA GEMM 128x128, dbuf (in-proj), bf16 out ------------------
__global__ __launch_bounds__(256) void mgemm_in(const ushort_t* __restrict__ A,
    const ushort_t* __restrict__ Bt, ushort_t* __restrict__ Cb,
    int M, int N, int K, int lda, int ldb)
{
    __shared__ ushort_t sA[2][128 * 32];
    __shared__ ushort_t sB[2][128 * 32];
    const int tid = threadIdx.x;
    const int lane = tid & 63, wv = tid >> 6;
    const int wm = wv >> 1, wn = wv & 1;
    const int swz = xcd_swz(blockIdx.y * gridDim.x + blockIdx.x, gridDim.x * gridDim.y);
    const int m0 = (swz / gridDim.x) * 128, n0 = (swz % gridDim.x) * 128;
    const int sr = tid >> 2;
    const int sc = (tid & 3) * 8;
    f32x4 acc[4][4] = {};

#pragma unroll
    for (int j = 0; j < 2; ++j) {
        int ra = sr + j * 64;
        __builtin_amdgcn_global_load_lds(
            (const uint_t*)(A + (size_t)(m0 + ra) * lda + sc),
            (uint_t*)(sA[0] + ra * 32 + sc), 16, 0, 0);
        __builtin_amdgcn_global_load_lds(
            (const uint_t*)(Bt + (size_t)(n0 + ra) * ldb + sc),
            (uint_t*)(sB[0] + ra * 32 + sc), 16, 0, 0);
    }
    __syncthreads();
    int cur = 0;
    for (int k0 = 0; k0 < K; k0 += 32) {
        if (k0 + 32 < K) {
            int nxt = cur ^ 1;
#pragma unroll
            for (int j = 0; j < 2; ++j) {
                int ra = sr + j * 64;
                __builtin_amdgcn_global_load_lds(
                    (const uint_t*)(A + (size_t)(m0 + ra) * lda + k0 + 32 + sc),
                    (uint_t*)(sA[nxt] + ra * 32 + sc), 16, 0, 0);
                __builtin_amdgcn_global_load_lds(
                    (const uint_t*)(Bt + (size_t)(n0 + ra) * ldb + k0 + 32 + sc),
                    (uint_t*)(sB[nxt] + ra * 32 + sc), 16, 0, 0);
            }
        }
        bf16x8 af[4], bfr[4];
#pragma unroll
        for (int i = 0; i < 4; ++i) {
            af[i]  = *(const bf16x8*)(sA[cur] + (wm * 64 + i * 16 + (lane & 15)) * 32 + (lane >> 4) * 8);
            bfr[i] = *(const bf16x8*)(sB[cur] + (wn * 64 + i * 16 + (lane & 15)) * 32 + (lane >> 4) * 8);
        }
#pragma unroll
        for (int i = 0; i < 4; ++i)
#pragma unroll
            for (int jj = 0; jj < 4; ++jj)
                acc[i][jj] = __builtin_amdgcn_mfma_f32_16x16x32_bf16(af[i], bfr[jj], acc[i][jj], 0, 0, 0);
        __syncthreads();
        cur ^= 1;
    }

    const int cr = (lane >> 4) * 4, cc = lane & 15;
#pragma unroll
    for (int i = 0; i < 4; ++i) {
        int mrow = m0 + wm * 64 + i * 16 + cr;
#pragma unroll
        for (int jj = 0; jj < 4; ++jj) {
            int ncol = n0 + wn * 64 + jj * 16 + cc;
#pragma unroll
            for (int r = 0; r < 4; ++r)
                Cb[(size_t)(mrow + r) * N + ncol] = f2b(acc[i][jj][r]);
        }
    }
}

// ---------------- MFMA GEMM 128xK split-K (N=96 W_x proj), dbuf ----------------
__global__ __launch_bounds__(256) void mgemm_sk(const ushort_t* __restrict__ A,
    const ushort_t* __restrict__ Bt, float* __restrict__ P,
    int M, int N, int Kslice, int lda, int ldb)
{
    __shared__ ushort_t sA[2][128 * 32];
    __shared__ ushort_t sB[2][128 * 32];
    const int tid = threadIdx.x;
    const int lane = tid & 63, wv = tid >> 6;
    const int wm = wv >> 1, wn = wv & 1;
    const int m0 = blockIdx.y * 128;
    const int kbase = blockIdx.z * Kslice;
    const int sr = tid >> 2;
    const int sc = (tid & 3) * 8;
    f32x4 acc[4][4] = {};

#pragma unroll
    for (int j = 0; j < 2; ++j) {
        int ra = sr + j * 64;
        __builtin_amdgcn_global_load_lds(
            (const uint_t*)(A + (size_t)(m0 + ra) * lda + kbase + sc),
            (uint_t*)(sA[0] + ra * 32 + sc), 16, 0, 0);
        int gb = ra; if (gb >= N) gb = N - 1;
        __builtin_amdgcn_global_load_lds(
            (const uint_t*)(Bt + (size_t)gb * ldb + kbase + sc),
            (uint_t*)(sB[0] + ra * 32 + sc), 16, 0, 0);
    }
    __syncthreads();
    int cur = 0;
    for (int k0 = kbase; k0 < kbase + Kslice; k0 += 32) {
        if (k0 + 32 < kbase + Kslice) {
            int nxt = cur ^ 1;
#pragma unroll
            for (int j = 0; j < 2; ++j) {
                int ra = sr + j * 64;
                __builtin_amdgcn_global_load_lds(
                    (const uint_t*)(A + (size_t)(m0 + ra) * lda + k0 + 32 + sc),
                    (uint_t*)(sA[nxt] + ra * 32 + sc), 16, 0, 0);
                int gb = ra; if (gb >= N) gb = N - 1;
                __builtin_amdgcn_global_load_lds(
                    (const uint_t*)(Bt + (size_t)gb * ldb + k0 + 32 + sc),
                    (uint_t*)(sB[nxt] + ra * 32 + sc), 16, 0, 0);
            }
        }
        bf16x8 af[4], bfr[4];
#pragma unroll
        for (int i = 0; i < 4; ++i) {
            af[i]  = *(const bf16x8*)(sA[cur] + (wm * 64 + i * 16 + (lane & 15)) * 32 + (lane >> 4) * 8);
            bfr[i] = *(const bf16x8*)(sB[cur] + (wn * 64 + i * 16 + (lane & 15)) * 32 + (lane >> 4) * 8);
        }
#pragma unroll
        for (int i = 0; i < 4; ++i)
#pragma unroll
            for (int jj = 0; jj < 4; ++jj)
                acc[i][jj] = __builtin_amdgcn_mfma_f32_16x16x32_bf16(af[i], bfr[jj], acc[i][jj], 0, 0, 0);
        __syncthreads();
        cur ^= 1;
    }

    const int cr = (lane >> 4) * 4, cc = lane & 15;
    float* Pz = P + (size_t)blockIdx.z * M * 96;
#pragma unroll
    for (int i = 0; i < 4; ++i) {
        int mrow = m0 + wm * 64 + i * 16 + cr;
#pragma unroll
        for (int jj = 0; jj < 4; ++jj) {
            int ncol = wn * 64 + jj * 16 + cc;
            if (ncol < 96) {
#pragma unroll
                for (int r = 0; r < 4; ++r)
                    Pz[(size_t)(mrow + r) * 96 + ncol] = acc[i][jj][r];
            }
        }
    }
}

// ---- fused: reduce split-K partials (cols 0:64 -> LDS bf16 A) + dt-proj GEMM --
__global__ __launch_bounds__(256) void mgemm_dtf(const float* __restrict__ P,
    const ushort_t* __restrict__ Wd, const float* __restrict__ bias,
    float* __restrict__ xdbl, ushort_t* __restrict__ dtfb)
{
    __shared__ ushort_t sA[2][128 * 36];   // pad 36/row-half: <=2-way banks
    __shared__ ushort_t sB[2][128 * 32];
    const int tid = threadIdx.x;
    const int lane = tid & 63, wv = tid >> 6;
    const int wm = wv >> 1, wn = wv & 1;
    const int n0 = blockIdx.x * 128, m0 = blockIdx.y * 128;

#pragma unroll
    for (int kh = 0; kh < 2; ++kh)
#pragma unroll
        for (int it = 0; it < 2; ++it) {
            int ci = tid + it * 256;             // 0..511
            int row = ci >> 2, cc = ci & 3;
            __builtin_amdgcn_global_load_lds(
                (const uint_t*)(Wd + (size_t)(n0 + row) * 64 + kh * 32 + cc * 8),
                (uint_t*)(sB[kh] + (size_t)ci * 8), 16, 0, 0);
        }

#pragma unroll
    for (int it = 0; it < 8; ++it) {
        int ci = tid + it * 256;                 // 0..2047
        int row = ci >> 4, c4 = (ci & 15) * 4;
        float s0 = 0.f, s1 = 0.f, s2 = 0.f, s3 = 0.f;
#pragma unroll
        for (int z = 0; z < 8; ++z) {
            f32x4 v = *(const f32x4*)(P + (size_t)z * 196608 + (size_t)(m0 + row) * 96 + c4);
            s0 += v[0]; s1 += v[1]; s2 += v[2]; s3 += v[3];
        }
        u16x4 o; o[0] = f2b(s0); o[1] = f2b(s1); o[2] = f2b(s2); o[3] = f2b(s3);
        int kh = c4 >> 5, cl = c4 & 31;
        *(u16x4*)(sA[kh] + row * 36 + cl) = o;
    }
    if (blockIdx.x == 0) {
#pragma unroll
        for (int it = 0; it < 4; ++it) {
            int ci = tid + it * 256;             // 0..1023
            int row = ci >> 3, c4 = (ci & 7) * 4;
            f32x4 s = {0.f, 0.f, 0.f, 0.f};
#pragma unroll
            for (int z = 0; z < 8; ++z) {
                f32x4 v = *(const f32x4*)(P + (size_t)z * 196608 + (size_t)(m0 + row) * 96 + 64 + c4);
                s[0] += v[0]; s[1] += v[1]; s[2] += v[2]; s[3] += v[3];
            }
            *(f32x4*)(xdbl + (size_t)(m0 + row) * 96 + 64 + c4) = s;
        }
    }
    __syncthreads();

    f32x4 acc[4][4] = {};
#pragma unroll
    for (int ks = 0; ks < 2; ++ks) {
        bf16x8 af[4], bfr[4];
#pragma unroll
        for (int i = 0; i < 4; ++i) {
            af[i]  = *(const bf16x8*)(sA[ks] + (wm * 64 + i * 16 + (lane & 15)) * 36 + (lane >> 4) * 8);
            bfr[i] = *(const bf16x8*)(sB[ks] + (wn * 64 + i * 16 + (lane & 15)) * 32 + (lane >> 4) * 8);
        }
#pragma unroll
        for (int i = 0; i < 4; ++i)
#pragma unroll
            for (int jj = 0; jj < 4; ++jj)
                acc[i][jj] = __builtin_amdgcn_mfma_f32_16x16x32_bf16(af[i], bfr[jj], acc[i][jj], 0, 0, 0);
    }

    const int cr = (lane >> 4) * 4, cc = lane & 15;
#pragma unroll
    for (int i = 0; i < 4; ++i) {
        int mrow = m0 + wm * 64 + i * 16 + cr;
#pragma unroll
        for (int jj = 0; jj < 4; ++jj) {
            int ncol = n0 + wn * 64 + jj * 16 + cc;
#pragma unroll
            for (int r = 0; r < 4; ++r) {
                float s = acc[i][jj][r] + bias[ncol];
                dtfb[(size_t)(mrow + r) * DIN + ncol] =
                    f2b((s > 20.f) ? s : log1pf(expf(s)));
            }
        }
    }
}

// ---------------- MFMA GEMM 128x64 split-K x2 (out-proj), f32 partial ----------
__global__ __launch_bounds__(256) void mgemm_o(const ushort_t* __restrict__ A,
    const ushort_t* __restrict__ Bt, float* __restrict__ P,
    int M, int N, int Kslice, int lda, int ldb)
{
    __shared__ ushort_t sA[2][128 * 32];
    __shared__ ushort_t sB[2][64 * 32];
    const int tid = threadIdx.x;
    const int lane = tid & 63, wv = tid >> 6;
    const int m0 = blockIdx.y * 128, n0 = blockIdx.x * 64;
    const int kbase = blockIdx.z * Kslice;
    const int sr = tid >> 2;
    const int sc = (tid & 3) * 8;
    f32x4 acc[2][4] = {};

#pragma unroll
    for (int j = 0; j < 2; ++j) {
        int ra = sr + j * 64;
        __builtin_amdgcn_global_load_lds(
            (const uint_t*)(A + (size_t)(m0 + ra) * lda + kbase + sc),
            (uint_t*)(sA[0] + ra * 32 + sc), 16, 0, 0);
    }
    __builtin_amdgcn_global_load_lds(
        (const uint_t*)(Bt + (size_t)(n0 + sr) * ldb + kbase + sc),
        (uint_t*)(sB[0] + sr * 32 + sc), 16, 0, 0);
    __syncthreads();
    int cur = 0;
    for (int k0 = kbase; k0 < kbase + Kslice; k0 += 32) {
        if (k0 + 32 < kbase + Kslice) {
            int nxt = cur ^ 1;
#pragma unroll
            for (int j = 0; j < 2; ++j) {
                int ra = sr + j * 64;
                __builtin_amdgcn_global_load_lds(
                    (const uint_t*)(A + (size_t)(m0 + ra) * lda + k0 + 32 + sc),
                    (uint_t*)(sA[nxt] + ra * 32 + sc), 16, 0, 0);
            }
            __builtin_amdgcn_global_load_lds(
                (const uint_t*)(Bt + (size_t)(n0 + sr) * ldb + k0 + 32 + sc),
                (uint_t*)(sB[nxt] + sr * 32 + sc), 16, 0, 0);
        }
        bf16x8 af[2], bfr[4];
#pragma unroll
        for (int i = 0; i < 2; ++i)
            af[i]  = *(const bf16x8*)(sA[cur] + (wv * 32 + i * 16 + (lane & 15)) * 32 + (lane >> 4) * 8);
#pragma unroll
        for (int jj = 0; jj < 4; ++jj)
            bfr[jj] = *(const bf16x8*)(sB[cur] + (jj * 16 + (lane & 15)) * 32 + (lane >> 4) * 8);
#pragma unroll
        for (int i = 0; i < 2; ++i)
#pragma unroll
            for (int jj = 0; jj < 4; ++jj)
                acc[i][jj] = __builtin_amdgcn_mfma_f32_16x16x32_bf16(af[i], bfr[jj], acc[i][jj], 0, 0, 0);
        __syncthreads();
        cur ^= 1;
    }

    const int cr = (lane >> 4) * 4, cc = lane & 15;
    float* Pz = P + (size_t)blockIdx.z * M * DM;
#pragma unroll
    for (int i = 0; i < 2; ++i) {
        int mrow = m0 + wv * 32 + i * 16 + cr;
#pragma unroll
        for (int jj = 0; jj < 4; ++jj) {
            int ncol = n0 + jj * 16 + cc;
#pragma unroll
            for (int r = 0; r < 4; ++r)
                Pz[(size_t)(mrow + r) * DM + ncol] = acc[i][jj][r];
        }
    }
}

// out-proj reduce: EPI 3 -> bf16 h; EPI 4 -> out = P0+P1+res
template<int EPI>
__global__ __launch_bounds__(256) void ored_k(const float* __restrict__ P,
    const float* __restrict__ res, float* __restrict__ Cf, ushort_t* __restrict__ Cb)
{
    int i = (blockIdx.x * 256 + threadIdx.x) * 4;
    f32x4 a = *(const f32x4*)(P + i);
    f32x4 b = *(const f32x4*)(P + 2097152 + i);
    if (EPI == 3) {
        u16x4 o;
#pragma unroll
        for (int e = 0; e < 4; ++e) o[e] = f2b(a[e] + b[e]);
        *(u16x4*)(Cb + i) = o;
    } else {
        f32x4 r = *(const f32x4*)(res + i);
        f32x4 o;
#pragma unroll
        for (int e = 0; e < 4; ++e) o[e] = a[e] + b[e] + r[e];
        *(f32x4*)(Cf + i) = o;
    }
}

// conv + silu, 8 channels per thread
__global__ __launch_bounds__(256) void conv8_k(const ushort_t* __restrict__ xzb,
    const float* __restrict__ cw, const float* __restrict__ cb,
    ushort_t* __restrict__ ucb)
{
    int idx8 = blockIdx.x * 256 + threadIdx.x;
    int d8 = (idx8 & 255) * 8;
    int t = (idx8 >> 8) & (L_ - 1);
    int b = idx8 >> 18;
    const ushort_t* base = xzb + (size_t)b * L_ * (2 * DIN) + d8;
    float acc[8];
    const float4* cb4 = (const float4*)(cb + d8);
    float4 cbl = cb4[0], cbh = cb4[1];
#pragma unroll
    for (int e = 0; e < 4; ++e) { acc[e] = ((const float*)&cbl)[e]; acc[4 + e] = ((const float*)&cbh)[e]; }
    float4 cwv[8];
#pragma unroll
    for (int e = 0; e < 8; ++e) cwv[e] = ((const float4*)cw)[d8 + e];
#pragma unroll
    for (int j = 0; j < 4; ++j) {
        int tt = t - 3 + j;
        if (tt >= 0) {
            u16x8 row = *(const u16x8*)(base + (size_t)tt * (2 * DIN));
#pragma unroll
            for (int e = 0; e < 8; ++e)
                acc[e] = fmaf(((const float*)&cwv[e])[j], b2f(row[e]), acc[e]);
        }
    }
    u16x8 ob;
#pragma unroll
    for (int e = 0; e < 8; ++e) {
        float v = acc[e] * sigmoidf_(acc[e]);
        ob[e] = f2b(v);
    }
    *(u16x8*)(ucb + (size_t)idx8 * 8) = ob;
}

// ---------------- chunk-parallel scan, 16 states per THREAD -------------------
// S1: local scan from zero over CHL=16 steps -> bnd_q, bnd_s.  1024 blocks.
__global__ __launch_bounds__(256, 2) void scan_s1(const ushort_t* __restrict__ dtfb,
    const ushort_t* __restrict__ ucb, const float* __restrict__ xdbl,
    const float* __restrict__ A_log,
    float* __restrict__ bnd_q, float* __restrict__ bnd_s)
{
    __shared__ ushort_t s_dt[CHL * 256];
    __shared__ ushort_t s_u[CHL * 256];
    __shared__ float sB[CHL * 16];
    const int tid = threadIdx.x;
    const int bx = blockIdx.x;
    const int dg = bx & 7, c = (bx >> 3) & (NCH - 1), b = bx >> 9;
    const int d = dg * 256 + tid;
    const int dbase = dg * 256;
    const int row0 = b * L_ + c * CHL;

    float A_dn[16];
#pragma unroll
    for (int j = 0; j < 4; ++j) {
        f32x4 av = *(const f32x4*)(A_log + (size_t)d * DS + j * 4);
#pragma unroll
        for (int e = 0; e < 4; ++e) A_dn[j * 4 + e] = -__expf(av[e]);
    }

    const int rr = tid >> 5, c16 = (tid & 31) * 8;
#pragma unroll
    for (int it = 0; it < 2; ++it) {
        int k = rr + it * 8;
        size_t gro = (size_t)(row0 + k) * DIN + dbase + c16;
        __builtin_amdgcn_global_load_lds((const uint_t*)(dtfb + gro),
            (uint_t*)(s_dt + k * 256 + c16), 16, 0, 0);
        __builtin_amdgcn_global_load_lds((const uint_t*)(ucb + gro),
            (uint_t*)(s_u + k * 256 + c16), 16, 0, 0);
    }
    sB[tid] = xdbl[(size_t)(row0 + (tid >> 4)) * 96 + 64 + (tid & 15)];
    __syncthreads();

    float q[16];
#pragma unroll
    for (int n = 0; n < 16; ++n) q[n] = 0.f;
    float s = 0.f;
    for (int k = 0; k < CHL; ++k) {
        float dtv = b2f(s_dt[k * 256 + tid]);
        float uv  = b2f(s_u[k * 256 + tid]);
        float dtu = dtv * uv;
        s += dtv;
        f32x4 Bq[4];
#pragma unroll
        for (int j = 0; j < 4; ++j) Bq[j] = *(const f32x4*)(sB + k * 16 + j * 4);
#pragma unroll
        for (int n = 0; n < 16; ++n)
            q[n] = fmaf(__expf(dtv * A_dn[n]), q[n], dtu * Bq[n >> 2][n & 3]);
    }
    float* qp = bnd_q + ((size_t)(b * NCH + c) * DIN + d) * 16;
#pragma unroll
    for (int j = 0; j < 4; ++j)
        *(f32x4*)(qp + j * 4) = (f32x4){q[j * 4], q[j * 4 + 1], q[j * 4 + 2], q[j * 4 + 3]};
    bnd_s[(size_t)(b * NCH + c) * DIN + d] = s;
}

// B2: in-place EXCLUSIVE prefix-combine over chunks: bnd_q[c] <- H_before_c.
// thread = (b, d, n); 65536 threads; coalesced (n fastest).
__global__ __launch_bounds__(256) void scan_b2(float* __restrict__ bnd_q,
    const float* __restrict__ bnd_s, const float* __restrict__ A_log)
{
    int glob = blockIdx.x * 256 + threadIdx.x;
    int n = glob & 15, d = (glob >> 4) & (DIN - 1), b = glob >> 15;
    float A_dn = -__expf(A_log[(size_t)d * DS + n]);
    float H = 0.f;
    for (int c = 0; c < NCH; ++c) {
        size_t idx = (size_t)(b * NCH + c) * DIN + d;
        float q = bnd_q[idx * 16 + n];
        float sv = bnd_s[idx];
        bnd_q[idx * 16 + n] = H;
        H = fmaf(__expf(A_dn * sv), H, q);
    }
}

// S2: read H_ini from bnd_q, rescan chunk, gate, vectorized store. 1024 blocks.
__global__ __launch_bounds__(256, 2) void scan_s2(const ushort_t* __restrict__ dtfb,
    const ushort_t* __restrict__ ucb_in, const float* __restrict__ xdbl,
    const ushort_t* __restrict__ xzb, const float* __restrict__ A_log,
    const float* __restrict__ Dvec, const float* __restrict__ bnd_q,
    ushort_t* __restrict__ ucb_out)
{
    __shared__ ushort_t s_dt[CHL * 256];   // reused for y output
    __shared__ ushort_t s_u[CHL * 256];
    __shared__ ushort_t s_z[CHL * 256];
    __shared__ float sBC[CHL * 32];
    const int tid = threadIdx.x;
    const int bx = blockIdx.x;
    const int dg = bx & 7, c = (bx >> 3) & (NCH - 1), b = bx >> 9;
    const int d = dg * 256 + tid;
    const int dbase = dg * 256;
    const int row0 = b * L_ + c * CHL;
    const float Dd = Dvec[d];

    float A_dn[16];
#pragma unroll
    for (int j = 0; j < 4; ++j) {
        f32x4 av = *(const f32x4*)(A_log + (size_t)d * DS + j * 4);
#pragma unroll
        for (int e = 0; e < 4; ++e) A_dn[j * 4 + e] = -__expf(av[e]);
    }

    const int rr = tid >> 5, c16 = (tid & 31) * 8;
#pragma unroll
    for (int it = 0; it < 2; ++it) {
        int k = rr + it * 8;
        size_t gro = (size_t)(row0 + k) * DIN + dbase + c16;
        __builtin_amdgcn_global_load_lds((const uint_t*)(dtfb + gro),
            (uint_t*)(s_dt + k * 256 + c16), 16, 0, 0);
        __builtin_amdgcn_global_load_lds((const uint_t*)(ucb_in + gro),
            (uint_t*)(s_u + k * 256 + c16), 16, 0, 0);
        __builtin_amdgcn_global_load_lds(
            (const uint_t*)(xzb + (size_t)(row0 + k) * (2 * DIN) + DIN + dbase + c16),
            (uint_t*)(s_z + k * 256 + c16), 16, 0, 0);
    }
#pragma unroll
    for (int j = 0; j < 2; ++j) {
        int idx = tid + j * 256;
        int t = idx >> 5, jj = idx & 31;
        sBC[idx] = xdbl[(size_t)(row0 + t) * 96 + 64 + (jj & 1) * 16 + (jj >> 1)];
    }

    // initial state for this chunk (precomputed by scan_b2)
    float h[16];
    const float* hp = bnd_q + ((size_t)(b * NCH + c) * DIN + d) * 16;
#pragma unroll
    for (int j = 0; j < 4; ++j) {
        f32x4 hv = *(const f32x4*)(hp + j * 4);
#pragma unroll
        for (int e = 0; e < 4; ++e) h[j * 4 + e] = hv[e];
    }
    __syncthreads();

    for (int k = 0; k < CHL; ++k) {
        float dtv = b2f(s_dt[k * 256 + tid]);
        float uv  = b2f(s_u[k * 256 + tid]);
        float z   = b2f(s_z[k * 256 + tid]);
        float dtu = dtv * uv;
        float y = uv * Dd;
        f32x4 bcq[8];
#pragma unroll
        for (int j = 0; j < 8; ++j) bcq[j] = *(const f32x4*)(sBC + k * 32 + j * 4);
#pragma unroll
        for (int n = 0; n < 16; ++n) {
            float Bv = bcq[n >> 1][(n & 1) * 2];
            float Cv = bcq[n >> 1][(n & 1) * 2 + 1];
            h[n] = fmaf(__expf(dtv * A_dn[n]), h[n], dtu * Bv);
            y = fmaf(h[n], Cv, y);
        }
        y *= z * sigmoidf_(z);
        s_dt[k * 256 + tid] = f2b(y);    // own slot, already consumed this step
    }
    __syncthreads();
#pragma unroll
    for (int it = 0; it < 2; ++it) {
        int k = rr + it * 8;
        *(u16x8*)(ucb_out + (size_t)(row0 + k) * DIN + dbase + c16) =
            *(const u16x8*)(s_dt + k * 256 + c16);
    }
}

extern "C" void kernel_launch(void* const* d_in, const int* in_sizes, int n_in,
                              void* d_out, int out_size, void* d_ws, size_t ws_size,
                              hipStream_t stream)
{
    (void)in_sizes; (void)n_in; (void)out_size; (void)ws_size;
    const float* x      = (const float*)d_in[0];
    const float* W_in   = (const float*)d_in[1];
    const float* conv_w = (const float*)d_in[2];
    const float* conv_b = (const float*)d_in[3];
    const float* W_x    = (const float*)d_in[4];
    const float* W_dt   = (const float*)d_in[5];
    const float* b_dt   = (const float*)d_in[6];
    const float* A_log  = (const float*)d_in[7];
    const float* Dv     = (const float*)d_in[8];
    const float* W_out  = (const float*)d_in[9];
    float* out = (float*)d_out;

    // workspace layout (overlays: bnd_s in pws; bnd_q = pwo — lifetimes disjoint)
    float* xdbl    = (float*)d_ws;                       //   196,608 f32
    float* pws     = xdbl + 196608;                      // 1,572,864 f32 (sk partials; dead after dtf)
    float* bnd_s   = pws;                                //   262,144 f32 overlay (s1->s2)
    ushort_t* dtfb = (ushort_t*)(pws + 1572864);         // 4,194,304 u16
    ushort_t* xzb  = dtfb + 4194304;                     // 8,388,608
    ushort_t* ucb  = xzb + 8388608;                      // 4,194,304
    ushort_t* xb   = ucb + 4194304;                      // 2,097,152 (x/h bf16)
    ushort_t* wib  = xb + 2097152;                       // 8,388,608
    ushort_t* wxb  = wib + 8388608;                      //   393,216
    ushort_t* wdb  = wxb + 393216;                       //   262,144
    ushort_t* wob  = wdb + 262144;                       // 4,194,304
    float* pwo     = (float*)(wob + 4194304);            // 4,194,304 f32 (out-proj partials)
    float* bnd_q   = pwo;                                // 4,194,304 f32 overlay (s1->s2)

    const int M = B_ * L_;
    const int NT = 2097152 + 8388608 + 393216 + 262144 + 4194304;
    f2b_all_k<<<(NT / 4) / 256, 256, 0, stream>>>(
        x, xb, 2097152, W_in, wib, 8388608, W_x, wxb, 393216,
        W_dt, wdb, 262144, W_out, wob, 4194304);

    for (int layer = 0; layer < 2; ++layer) {
        // xzb = bf16( h @ W_in^T )  [M, 4096]
        mgemm_in<<<dim3(4096 / 128, M / 128), 256, 0, stream>>>(
            xb, wib + (size_t)layer * 4194304, xzb, M, 2 * DIN, DM, DM, DM);
        // ucb = bf16(silu(conv(u) + b))
        conv8_k<<<(B_ * L_ * DIN / 8) / 256, 256, 0, stream>>>(
            xzb, conv_w + (size_t)layer * DIN * 4, conv_b + (size_t)layer * DIN, ucb);
        // pws[z] = partial (u @ W_x^T) over K-slices  [M, 96] x8
        mgemm_sk<<<dim3(1, M / 128, 8), 256, 0, stream>>>(
            ucb, wxb + (size_t)layer * 196608, pws, M, 96, DIN / 8, DIN, DIN);
        // fused: reduce partials + dt-proj softplus -> dtfb; bx==0 writes xdbl[:,64:96]
        mgemm_dtf<<<dim3(16, 16), 256, 0, stream>>>(
            pws, wdb + (size_t)layer * 131072, b_dt + (size_t)layer * DIN, xdbl, dtfb);
        // chunk-parallel scan: local scans -> prefix combine -> rescan
        const float* Al = A_log + (size_t)layer * DIN * DS;
        scan_s1<<<B_ * NCH * 8, 256, 0, stream>>>(dtfb, ucb, xdbl, Al, bnd_q, bnd_s);
        scan_b2<<<(B_ * DIN * 16) / 256, 256, 0, stream>>>(bnd_q, bnd_s, Al);
        scan_s2<<<B_ * NCH * 8, 256, 0, stream>>>(dtfb, ucb, xdbl, xzb, Al,
            Dv + (size_t)layer * DIN, bnd_q, ucb);
        // out-proj split-K x2 -> partials, then fused reduce
        mgemm_o<<<dim3(1024 / 64, M / 128, 2), 256, 0, stream>>>(
            ucb, wob + (size_t)layer * 2097152, pwo, M, DM, DIN / 2, DIN, DIN);
        if (layer == 0)
            ored_k<3><<<(2097152 / 4) / 256, 256, 0, stream>>>(pwo, nullptr, nullptr, xb);
        else
            ored_k<4><<<(2097152 / 4) / 256, 256, 0, stream>>>(pwo, x, out, nullptr);
    }
}